// Round 6
// baseline (1424.832 us; speedup 1.0000x reference)
//
#include <hip/hip_runtime.h>
#include <hip/hip_bf16.h>
#include <math.h>

#define N_NODES 50000
#define N_EDGES 800000
#define NH 4
#define HC 256
#define TOT_E (N_EDGES + N_NODES)
#define SCAN_NB ((N_NODES + 255) / 256)

static __device__ __forceinline__ float lrelu(float x) { return x >= 0.f ? x : 0.2f * x; }

// ---------------- CSR build (counting sort by dst) ----------------
__global__ __launch_bounds__(256) void count_kernel(const int* __restrict__ ei,
                                                    int* __restrict__ cnt) {
    int i = blockIdx.x * blockDim.x + threadIdx.x;
    if (i >= TOT_E) return;
    int dst = (i < N_EDGES) ? ei[N_EDGES + i] : (i - N_EDGES);  // self-loops appended
    atomicAdd(&cnt[dst], 1);
}

// device-wide exclusive scan over cnt[N_NODES] -> offs, 3 kernels
__global__ __launch_bounds__(256) void scan1_kernel(const int* __restrict__ cnt,
                                                    int* __restrict__ offs,
                                                    int* __restrict__ bsum) {
    __shared__ int sm[256];
    const int t = threadIdx.x;
    const int base = blockIdx.x * 256;
    int v = (base + t < N_NODES) ? cnt[base + t] : 0;
    sm[t] = v;
    __syncthreads();
#pragma unroll
    for (int d = 1; d < 256; d <<= 1) {
        int add = (t >= d) ? sm[t - d] : 0;
        __syncthreads();
        sm[t] += add;
        __syncthreads();
    }
    if (base + t < N_NODES) offs[base + t] = sm[t] - v;  // local exclusive
    if (t == 255) bsum[blockIdx.x] = sm[255];
}

__global__ __launch_bounds__(256) void scan2_kernel(int* __restrict__ bsum,
                                                    int* __restrict__ total) {
    __shared__ int sm[256];
    const int t = threadIdx.x;
    int v = (t < SCAN_NB) ? bsum[t] : 0;
    sm[t] = v;
    __syncthreads();
#pragma unroll
    for (int d = 1; d < 256; d <<= 1) {
        int add = (t >= d) ? sm[t - d] : 0;
        __syncthreads();
        sm[t] += add;
        __syncthreads();
    }
    if (t < SCAN_NB) bsum[t] = sm[t] - v;  // exclusive block offsets
    if (t == 255) *total = sm[255];        // == TOT_E
}

__global__ __launch_bounds__(256) void scan3_kernel(int* __restrict__ offs,
                                                    const int* __restrict__ bsum) {
    int i = blockIdx.x * blockDim.x + threadIdx.x;
    if (i < N_NODES) offs[i] += bsum[i >> 8];
}

__global__ __launch_bounds__(256) void scatter_kernel(const int* __restrict__ ei,
                                                      const int* __restrict__ offs,
                                                      int* __restrict__ cursor,
                                                      int* __restrict__ ssrc) {
    int i = blockIdx.x * blockDim.x + threadIdx.x;
    if (i >= TOT_E) return;
    int src, dst;
    if (i < N_EDGES) { src = ei[i]; dst = ei[N_EDGES + i]; }
    else             { src = i - N_EDGES; dst = src; }
    int pos = offs[dst] + atomicAdd(&cursor[dst], 1);
    ssrc[pos] = src;
}

// ---------------- fp32 GEMM: C[M,256] = relu(bn(A))[M,K] @ B[K,256] ----------------
// 128x128 tile, 8x8 microtile, 256 threads (16x16).
// Optional fused input BN+ReLU (bnscale/bnshift, nullptr = identity).
// Fused epilogue: als/ald head-dots (exact, no atomics).
__global__ __launch_bounds__(256) void gemm_kernel(const float* __restrict__ A,
                                                   const float* __restrict__ B,
                                                   float* __restrict__ C,
                                                   const float* __restrict__ bnscale,
                                                   const float* __restrict__ bnshift,
                                                   const float* __restrict__ a_s,
                                                   const float* __restrict__ a_d,
                                                   float* __restrict__ als,
                                                   float* __restrict__ ald,
                                                   int M, int K) {
    __shared__ float As[16][128];  // [k][m]
    __shared__ float Bs[16][128];  // [k][n]
    const int t = threadIdx.x;
    const int tx = t & 15, ty = t >> 4;
    const int bm = blockIdx.x * 128;
    const int bn = blockIdx.y * 128;
    const int ar = t >> 2;          // 0..63   A staging row within half
    const int ak = (t & 3) << 2;    // 0,4,8,12
    const int bk = t >> 5;          // 0..7    B staging k within half
    const int bn4 = (t & 31) << 2;  // 0..124
    float acc[8][8] = {{0.f}};
    for (int k0 = 0; k0 < K; k0 += 16) {
        float4 sc = make_float4(1.f, 1.f, 1.f, 1.f);
        float4 sh = make_float4(0.f, 0.f, 0.f, 0.f);
        if (bnscale) {
            sc = *(const float4*)(bnscale + k0 + ak);
            sh = *(const float4*)(bnshift + k0 + ak);
        }
#pragma unroll
        for (int r = 0; r < 2; ++r) {
            int row = bm + r * 64 + ar;
            float4 a4 = make_float4(0.f, 0.f, 0.f, 0.f);
            if (row < M) a4 = *(const float4*)(A + (size_t)row * K + k0 + ak);
            if (bnscale) {  // fused relu(bn(.)) of the previous layer's output
                a4.x = fmaxf(0.f, fmaf(a4.x, sc.x, sh.x));
                a4.y = fmaxf(0.f, fmaf(a4.y, sc.y, sh.y));
                a4.z = fmaxf(0.f, fmaf(a4.z, sc.z, sh.z));
                a4.w = fmaxf(0.f, fmaf(a4.w, sc.w, sh.w));
            }
            As[ak + 0][r * 64 + ar] = a4.x;
            As[ak + 1][r * 64 + ar] = a4.y;
            As[ak + 2][r * 64 + ar] = a4.z;
            As[ak + 3][r * 64 + ar] = a4.w;
        }
#pragma unroll
        for (int r = 0; r < 2; ++r) {
            int kk = r * 8 + bk;
            *(float4*)&Bs[kk][bn4] = *(const float4*)(B + (size_t)(k0 + kk) * HC + bn + bn4);
        }
        __syncthreads();
#pragma unroll
        for (int kk = 0; kk < 16; ++kk) {
            float a[8], b[8];
            *(float4*)&a[0] = *(const float4*)&As[kk][ty * 8];
            *(float4*)&a[4] = *(const float4*)&As[kk][ty * 8 + 4];
            *(float4*)&b[0] = *(const float4*)&Bs[kk][tx * 8];
            *(float4*)&b[4] = *(const float4*)&Bs[kk][tx * 8 + 4];
#pragma unroll
            for (int i = 0; i < 8; ++i)
#pragma unroll
                for (int j = 0; j < 8; ++j)
                    acc[i][j] = fmaf(a[i], b[j], acc[i][j]);
        }
        __syncthreads();
    }
    // C write
#pragma unroll
    for (int i = 0; i < 8; ++i) {
        int row = bm + ty * 8 + i;
        if (row < M) {
            *(float4*)(C + (size_t)row * HC + bn + tx * 8) =
                make_float4(acc[i][0], acc[i][1], acc[i][2], acc[i][3]);
            *(float4*)(C + (size_t)row * HC + bn + tx * 8 + 4) =
                make_float4(acc[i][4], acc[i][5], acc[i][6], acc[i][7]);
        }
    }
    // fused als/ald epilogue: head = (bn>>6) + (tx>>3), cols tx*8..tx*8+7
    const int ch0 = bn + tx * 8;
    float asv[8], adv[8];
#pragma unroll
    for (int j = 0; j < 8; ++j) { asv[j] = a_s[ch0 + j]; adv[j] = a_d[ch0 + j]; }
#pragma unroll
    for (int i = 0; i < 8; ++i) {
        int row = bm + ty * 8 + i;
        float ps = 0.f, pd = 0.f;
#pragma unroll
        for (int j = 0; j < 8; ++j) {
            ps = fmaf(acc[i][j], asv[j], ps);
            pd = fmaf(acc[i][j], adv[j], pd);
        }
#pragma unroll
        for (int d = 1; d < 8; d <<= 1) {  // reduce the 8 lanes of one head-half
            ps += __shfl_xor(ps, d, 64);
            pd += __shfl_xor(pd, d, 64);
        }
        if ((tx & 7) == 0 && row < M) {
            int head = (bn >> 6) + (tx >> 3);
            als[row * NH + head] = ps;
            ald[row * NH + head] = pd;
        }
    }
}

// ---------------- GAT aggregation: one wave per dst ----------------
// Chunk-parallel edge prep (coalesced ssrc, lane-per-edge logits, wave-reduced
// chunk max/sum) + software-pipelined independent h-row gather.
__global__ __launch_bounds__(256) void gat_edge_kernel(const float* __restrict__ h,
                                                       const int* __restrict__ offs,
                                                       const int* __restrict__ ssrc,
                                                       const float* __restrict__ als,
                                                       const float* __restrict__ ald,
                                                       const float* __restrict__ bias,
                                                       float* __restrict__ out) {
    __shared__ float ex_sm[4][64][NH];
    __shared__ int   src_sm[4][64];
    const int lane = threadIdx.x & 63;
    const int w = threadIdx.x >> 6;
    const int v = (blockIdx.x << 2) + w;
    if (v >= N_NODES) return;
    const int hh = lane >> 4;
    const float4 aldv4 = *(const float4*)(ald + v * NH);
    const int beg = offs[v], end = offs[v + 1];  // degree >= 1 (self-loop)

    float4 m4 = make_float4(-INFINITY, -INFINITY, -INFINITY, -INFINITY);
    float4 s4 = make_float4(0.f, 0.f, 0.f, 0.f);
    float ax = 0.f, ay = 0.f, az = 0.f, aw = 0.f;

    for (int c0 = beg; c0 < end; c0 += 64) {
        const int n = min(64, end - c0);
        // ---- phase 1: lane-per-edge prep ----
        const int s0 = ssrc[c0];  // scalar-ish broadcast (pad value)
        int srcl = s0;
        float4 e4 = make_float4(-INFINITY, -INFINITY, -INFINITY, -INFINITY);
        if (lane < n) {
            srcl = ssrc[c0 + lane];  // coalesced
            float4 a4 = *(const float4*)(als + srcl * NH);
            e4.x = lrelu(a4.x + aldv4.x);
            e4.y = lrelu(a4.y + aldv4.y);
            e4.z = lrelu(a4.z + aldv4.z);
            e4.w = lrelu(a4.w + aldv4.w);
        }
        // chunk max per head
        float4 cm = e4;
#pragma unroll
        for (int d = 1; d < 64; d <<= 1) {
            cm.x = fmaxf(cm.x, __shfl_xor(cm.x, d, 64));
            cm.y = fmaxf(cm.y, __shfl_xor(cm.y, d, 64));
            cm.z = fmaxf(cm.z, __shfl_xor(cm.z, d, 64));
            cm.w = fmaxf(cm.w, __shfl_xor(cm.w, d, 64));
        }
        const float4 mn = make_float4(fmaxf(m4.x, cm.x), fmaxf(m4.y, cm.y),
                                      fmaxf(m4.z, cm.z), fmaxf(m4.w, cm.w));
        const float4 r4 = make_float4(__expf(m4.x - mn.x), __expf(m4.y - mn.y),
                                      __expf(m4.z - mn.z), __expf(m4.w - mn.w));
        float4 ex4;  // 0 for inactive lanes (e = -inf, mn finite)
        ex4.x = __expf(e4.x - mn.x);
        ex4.y = __expf(e4.y - mn.y);
        ex4.z = __expf(e4.z - mn.z);
        ex4.w = __expf(e4.w - mn.w);
        src_sm[w][lane] = srcl;
        *(float4*)&ex_sm[w][lane][0] = ex4;
        // wave sum of ex per head
        float4 se = ex4;
#pragma unroll
        for (int d = 1; d < 64; d <<= 1) {
            se.x += __shfl_xor(se.x, d, 64);
            se.y += __shfl_xor(se.y, d, 64);
            se.z += __shfl_xor(se.z, d, 64);
            se.w += __shfl_xor(se.w, d, 64);
        }
        s4 = make_float4(fmaf(s4.x, r4.x, se.x), fmaf(s4.y, r4.y, se.y),
                         fmaf(s4.z, r4.z, se.z), fmaf(s4.w, r4.w, se.w));
        const float rh = hh == 0 ? r4.x : hh == 1 ? r4.y : hh == 2 ? r4.z : r4.w;
        ax *= rh; ay *= rh; az *= rh; aw *= rh;
        m4 = mn;

        // ---- phase 2: pipelined gather-accumulate (groups of 4) ----
        const int trip = (n + 3) & ~3;  // tail padded with (s0, weight 0)
        int sj0 = src_sm[w][0], sj1 = src_sm[w][1];
        int sj2 = src_sm[w][2], sj3 = src_sm[w][3];
        float wj0 = ex_sm[w][0][hh], wj1 = ex_sm[w][1][hh];
        float wj2 = ex_sm[w][2][hh], wj3 = ex_sm[w][3][hh];
        const int co = lane << 2;
        for (int j = 0; j < trip; j += 4) {
            const float4 r0 = *(const float4*)(h + (size_t)sj0 * HC + co);
            const float4 r1 = *(const float4*)(h + (size_t)sj1 * HC + co);
            const float4 r2 = *(const float4*)(h + (size_t)sj2 * HC + co);
            const float4 r3 = *(const float4*)(h + (size_t)sj3 * HC + co);
            const float u0 = wj0, u1 = wj1, u2 = wj2, u3 = wj3;
            if (j + 4 < trip) {  // preload next group's (src, w) under load latency
                sj0 = src_sm[w][j + 4]; wj0 = ex_sm[w][j + 4][hh];
                sj1 = src_sm[w][j + 5]; wj1 = ex_sm[w][j + 5][hh];
                sj2 = src_sm[w][j + 6]; wj2 = ex_sm[w][j + 6][hh];
                sj3 = src_sm[w][j + 7]; wj3 = ex_sm[w][j + 7][hh];
            }
            ax = fmaf(u0, r0.x, ax); ay = fmaf(u0, r0.y, ay);
            az = fmaf(u0, r0.z, az); aw = fmaf(u0, r0.w, aw);
            ax = fmaf(u1, r1.x, ax); ay = fmaf(u1, r1.y, ay);
            az = fmaf(u1, r1.z, az); aw = fmaf(u1, r1.w, aw);
            ax = fmaf(u2, r2.x, ax); ay = fmaf(u2, r2.y, ay);
            az = fmaf(u2, r2.z, az); aw = fmaf(u2, r2.w, aw);
            ax = fmaf(u3, r3.x, ax); ay = fmaf(u3, r3.y, ay);
            az = fmaf(u3, r3.z, az); aw = fmaf(u3, r3.w, aw);
        }
    }

    const float sh = hh == 0 ? s4.x : hh == 1 ? s4.y : hh == 2 ? s4.z : s4.w;
    const float inv = 1.f / (sh + 1e-16f);
    const float4 b4 = *(const float4*)(bias + (lane << 2));
    *(float4*)(out + (size_t)v * HC + (lane << 2)) =
        make_float4(fmaf(ax, inv, b4.x), fmaf(ay, inv, b4.y),
                    fmaf(az, inv, b4.z), fmaf(aw, inv, b4.w));
}

// ---------------- BatchNorm stats (apply is fused into consumers) ----------------
__global__ __launch_bounds__(256) void bn_stats_kernel(const float* __restrict__ y,
                                                       double* __restrict__ sum,
                                                       double* __restrict__ sqsum) {
    const int t = threadIdx.x;  // channel
    const int r0 = blockIdx.x * 128;
    const int r1 = min(r0 + 128, N_NODES);
    float s = 0.f, q = 0.f;
    for (int r = r0; r < r1; ++r) {
        float v = y[(size_t)r * HC + t];
        s += v;
        q = fmaf(v, v, q);
    }
    atomicAdd(&sum[t], (double)s);
    atomicAdd(&sqsum[t], (double)q);
}

__global__ void bn_finalize_kernel(const double* __restrict__ sum,
                                   const double* __restrict__ sqsum,
                                   const float* __restrict__ g,
                                   const float* __restrict__ be,
                                   float* __restrict__ scale,
                                   float* __restrict__ shift) {
    int t = threadIdx.x;
    double mean = sum[t] / (double)N_NODES;
    double var = sqsum[t] / (double)N_NODES - mean * mean;
    float sc = g[t] * rsqrtf((float)var + 1e-5f);
    scale[t] = sc;
    shift[t] = be[t] - (float)mean * sc;
}

// ---------------- final linear: out[N,32] = relu(bn(y))[N,256] @ Wl[256,32] + bl ----
__global__ __launch_bounds__(256) void linear_kernel(const float* __restrict__ y,
                                                     const float* __restrict__ Wl,
                                                     const float* __restrict__ bl,
                                                     const float* __restrict__ scale,
                                                     const float* __restrict__ shift,
                                                     float* __restrict__ out) {
    __shared__ float Wls[256 * 32];
    __shared__ float scs[256], shs[256];
    const int t = threadIdx.x;
    for (int i = t; i < 256 * 32; i += 256) Wls[i] = Wl[i];
    scs[t] = scale[t];
    shs[t] = shift[t];
    __syncthreads();
    int gid = blockIdx.x * 256 + t;
    if (gid >= N_NODES * 32) return;
    int n = gid >> 5, j = gid & 31;
    float acc = bl[j];
    const float4* yrow = (const float4*)(y + (size_t)n * HC);
#pragma unroll
    for (int k4 = 0; k4 < 64; ++k4) {
        float4 y4 = yrow[k4];
        int k = k4 << 2;
        y4.x = fmaxf(0.f, fmaf(y4.x, scs[k + 0], shs[k + 0]));
        y4.y = fmaxf(0.f, fmaf(y4.y, scs[k + 1], shs[k + 1]));
        y4.z = fmaxf(0.f, fmaf(y4.z, scs[k + 2], shs[k + 2]));
        y4.w = fmaxf(0.f, fmaf(y4.w, scs[k + 3], shs[k + 3]));
        acc = fmaf(y4.x, Wls[(k + 0) * 32 + j], acc);
        acc = fmaf(y4.y, Wls[(k + 1) * 32 + j], acc);
        acc = fmaf(y4.z, Wls[(k + 2) * 32 + j], acc);
        acc = fmaf(y4.w, Wls[(k + 3) * 32 + j], acc);
    }
    out[gid] = acc;
}

extern "C" void kernel_launch(void* const* d_in, const int* in_sizes, int n_in,
                              void* d_out, int out_size, void* d_ws, size_t ws_size,
                              hipStream_t stream) {
    const float* x     = (const float*)d_in[0];
    const int* ei_sp   = (const int*)d_in[1];
    const int* ei_tp   = (const int*)d_in[2];
    const float* Wl    = (const float*)d_in[27];
    const float* bl    = (const float*)d_in[28];

    // ---- workspace layout ----
    char* ws = (char*)d_ws;
    size_t off = 0;
    auto alloc = [&](size_t bytes) -> char* {
        char* p = ws + off;
        off = (off + bytes + 255) & ~(size_t)255;
        return p;
    };
    float* buf0    = (float*)alloc((size_t)N_NODES * HC * 4);  // gemm output h
    float* buf1    = (float*)alloc((size_t)N_NODES * HC * 4);  // gat output / next input
    float* als     = (float*)alloc((size_t)N_NODES * NH * 4);
    float* ald     = (float*)alloc((size_t)N_NODES * NH * 4);
    int*   offs_sp = (int*)alloc((size_t)(N_NODES + 1) * 4);
    int*   offs_tp = (int*)alloc((size_t)(N_NODES + 1) * 4);
    int*   src_sp  = (int*)alloc((size_t)TOT_E * 4);
    int*   src_tp  = (int*)alloc((size_t)TOT_E * 4);
    int*   cnt     = (int*)alloc((size_t)N_NODES * 4);
    int*   bsum    = (int*)alloc((size_t)SCAN_NB * 4);
    double* bnsum  = (double*)alloc(256 * 8 * 2);  // sum + sqsum contiguous
    double* bnsq   = bnsum + 256;
    float* scale   = (float*)alloc(256 * 4);
    float* shift   = (float*)alloc(256 * 4);
    (void)ws_size; (void)in_sizes; (void)n_in; (void)out_size;

    const int EB = (TOT_E + 255) / 256;

    // ---- build CSR for both edge types (once per call) ----
    hipMemsetAsync(cnt, 0, (size_t)N_NODES * 4, stream);
    count_kernel<<<EB, 256, 0, stream>>>(ei_sp, cnt);
    scan1_kernel<<<SCAN_NB, 256, 0, stream>>>(cnt, offs_sp, bsum);
    scan2_kernel<<<1, 256, 0, stream>>>(bsum, offs_sp + N_NODES);
    scan3_kernel<<<SCAN_NB, 256, 0, stream>>>(offs_sp, bsum);
    hipMemsetAsync(cnt, 0, (size_t)N_NODES * 4, stream);
    scatter_kernel<<<EB, 256, 0, stream>>>(ei_sp, offs_sp, cnt, src_sp);

    hipMemsetAsync(cnt, 0, (size_t)N_NODES * 4, stream);
    count_kernel<<<EB, 256, 0, stream>>>(ei_tp, cnt);
    scan1_kernel<<<SCAN_NB, 256, 0, stream>>>(cnt, offs_tp, bsum);
    scan2_kernel<<<1, 256, 0, stream>>>(bsum, offs_tp + N_NODES);
    scan3_kernel<<<SCAN_NB, 256, 0, stream>>>(offs_tp, bsum);
    hipMemsetAsync(cnt, 0, (size_t)N_NODES * 4, stream);
    scatter_kernel<<<EB, 256, 0, stream>>>(ei_tp, offs_tp, cnt, src_tp);

    // ---- 4 GAT + BN(+fused apply) layers ----
    const int NB4 = (N_NODES + 3) / 4;             // wave-per-node kernels
    const dim3 ggrid((N_NODES + 127) / 128, 2);    // gemm grid (128x128 tiles)
    for (int L = 0; L < 4; ++L) {
        const float* in = (L == 0) ? x : buf1;
        const int K = (L == 0) ? 128 : 256;
        const float* bns = (L == 0) ? nullptr : scale;  // prev layer's BN, fused
        const float* bnh = (L == 0) ? nullptr : shift;
        const int* offs = (L < 2) ? offs_sp : offs_tp;
        const int* ssrc = (L < 2) ? src_sp : src_tp;
        const int base = 3 + L * 6;
        const float* W  = (const float*)d_in[base + 0];
        const float* as_ = (const float*)d_in[base + 1];
        const float* ad_ = (const float*)d_in[base + 2];
        const float* b_  = (const float*)d_in[base + 3];
        const float* g_  = (const float*)d_in[base + 4];
        const float* be_ = (const float*)d_in[base + 5];

        gemm_kernel<<<ggrid, 256, 0, stream>>>(in, W, buf0, bns, bnh,
                                               as_, ad_, als, ald, N_NODES, K);
        gat_edge_kernel<<<NB4, 256, 0, stream>>>(buf0, offs, ssrc, als, ald, b_, buf1);

        hipMemsetAsync(bnsum, 0, 256 * 8 * 2, stream);
        bn_stats_kernel<<<(N_NODES + 127) / 128, 256, 0, stream>>>(buf1, bnsum, bnsq);
        bn_finalize_kernel<<<1, 256, 0, stream>>>(bnsum, bnsq, g_, be_, scale, shift);
    }

    // ---- final linear (fused relu(bn(.)) of layer 4) ----
    linear_kernel<<<(N_NODES * 32 + 255) / 256, 256, 0, stream>>>(buf1, Wl, bl,
                                                                  scale, shift,
                                                                  (float*)d_out);
}

// Round 7
// 1177.669 us; speedup vs baseline: 1.2099x; 1.2099x over previous
//
#include <hip/hip_runtime.h>
#include <hip/hip_bf16.h>
#include <hip/hip_fp16.h>
#include <math.h>

#define N_NODES 50000
#define N_EDGES 800000
#define NH 4
#define HC 256
#define TOT_E (N_EDGES + N_NODES)
#define SCAN_NB ((N_NODES + 255) / 256)

static __device__ __forceinline__ float lrelu(float x) { return x >= 0.f ? x : 0.2f * x; }

// ---------------- CSR build (counting sort by dst) ----------------
__global__ __launch_bounds__(256) void count_kernel(const int* __restrict__ ei,
                                                    int* __restrict__ cnt) {
    int i = blockIdx.x * blockDim.x + threadIdx.x;
    if (i >= TOT_E) return;
    int dst = (i < N_EDGES) ? ei[N_EDGES + i] : (i - N_EDGES);  // self-loops appended
    atomicAdd(&cnt[dst], 1);
}

// device-wide exclusive scan over cnt[N_NODES] -> offs, 3 kernels
__global__ __launch_bounds__(256) void scan1_kernel(const int* __restrict__ cnt,
                                                    int* __restrict__ offs,
                                                    int* __restrict__ bsum) {
    __shared__ int sm[256];
    const int t = threadIdx.x;
    const int base = blockIdx.x * 256;
    int v = (base + t < N_NODES) ? cnt[base + t] : 0;
    sm[t] = v;
    __syncthreads();
#pragma unroll
    for (int d = 1; d < 256; d <<= 1) {
        int add = (t >= d) ? sm[t - d] : 0;
        __syncthreads();
        sm[t] += add;
        __syncthreads();
    }
    if (base + t < N_NODES) offs[base + t] = sm[t] - v;  // local exclusive
    if (t == 255) bsum[blockIdx.x] = sm[255];
}

__global__ __launch_bounds__(256) void scan2_kernel(int* __restrict__ bsum,
                                                    int* __restrict__ total) {
    __shared__ int sm[256];
    const int t = threadIdx.x;
    int v = (t < SCAN_NB) ? bsum[t] : 0;
    sm[t] = v;
    __syncthreads();
#pragma unroll
    for (int d = 1; d < 256; d <<= 1) {
        int add = (t >= d) ? sm[t - d] : 0;
        __syncthreads();
        sm[t] += add;
        __syncthreads();
    }
    if (t < SCAN_NB) bsum[t] = sm[t] - v;  // exclusive block offsets
    if (t == 255) *total = sm[255];        // == TOT_E
}

__global__ __launch_bounds__(256) void scan3_kernel(int* __restrict__ offs,
                                                    const int* __restrict__ bsum) {
    int i = blockIdx.x * blockDim.x + threadIdx.x;
    if (i < N_NODES) offs[i] += bsum[i >> 8];
}

__global__ __launch_bounds__(256) void scatter_kernel(const int* __restrict__ ei,
                                                      const int* __restrict__ offs,
                                                      int* __restrict__ cursor,
                                                      int* __restrict__ ssrc) {
    int i = blockIdx.x * blockDim.x + threadIdx.x;
    if (i >= TOT_E) return;
    int src, dst;
    if (i < N_EDGES) { src = ei[i]; dst = ei[N_EDGES + i]; }
    else             { src = i - N_EDGES; dst = src; }
    int pos = offs[dst] + atomicAdd(&cursor[dst], 1);
    ssrc[pos] = src;
}

// ---------------- fp32 GEMM: C[M,256] = relu(bn(A))[M,K] @ B[K,256] ----------------
// 128x128 tile, 8x8 microtile, 256 threads (16x16).
// C is written in FP16 (consumed only by the gather kernel).
// Optional fused input BN+ReLU (bnscale/bnshift, nullptr = identity).
// Fused epilogue: als/ald head-dots from fp32 accumulators (exact, no atomics).
__global__ __launch_bounds__(256) void gemm_kernel(const float* __restrict__ A,
                                                   const float* __restrict__ B,
                                                   __half* __restrict__ C,
                                                   const float* __restrict__ bnscale,
                                                   const float* __restrict__ bnshift,
                                                   const float* __restrict__ a_s,
                                                   const float* __restrict__ a_d,
                                                   float* __restrict__ als,
                                                   float* __restrict__ ald,
                                                   int M, int K) {
    __shared__ float As[16][128];  // [k][m]
    __shared__ float Bs[16][128];  // [k][n]
    const int t = threadIdx.x;
    const int tx = t & 15, ty = t >> 4;
    const int bm = blockIdx.x * 128;
    const int bn = blockIdx.y * 128;
    const int ar = t >> 2;          // 0..63   A staging row within half
    const int ak = (t & 3) << 2;    // 0,4,8,12
    const int bk = t >> 5;          // 0..7    B staging k within half
    const int bn4 = (t & 31) << 2;  // 0..124
    float acc[8][8] = {{0.f}};
    for (int k0 = 0; k0 < K; k0 += 16) {
        float4 sc = make_float4(1.f, 1.f, 1.f, 1.f);
        float4 sh = make_float4(0.f, 0.f, 0.f, 0.f);
        if (bnscale) {
            sc = *(const float4*)(bnscale + k0 + ak);
            sh = *(const float4*)(bnshift + k0 + ak);
        }
#pragma unroll
        for (int r = 0; r < 2; ++r) {
            int row = bm + r * 64 + ar;
            float4 a4 = make_float4(0.f, 0.f, 0.f, 0.f);
            if (row < M) a4 = *(const float4*)(A + (size_t)row * K + k0 + ak);
            if (bnscale) {  // fused relu(bn(.)) of the previous layer's output
                a4.x = fmaxf(0.f, fmaf(a4.x, sc.x, sh.x));
                a4.y = fmaxf(0.f, fmaf(a4.y, sc.y, sh.y));
                a4.z = fmaxf(0.f, fmaf(a4.z, sc.z, sh.z));
                a4.w = fmaxf(0.f, fmaf(a4.w, sc.w, sh.w));
            }
            As[ak + 0][r * 64 + ar] = a4.x;
            As[ak + 1][r * 64 + ar] = a4.y;
            As[ak + 2][r * 64 + ar] = a4.z;
            As[ak + 3][r * 64 + ar] = a4.w;
        }
#pragma unroll
        for (int r = 0; r < 2; ++r) {
            int kk = r * 8 + bk;
            *(float4*)&Bs[kk][bn4] = *(const float4*)(B + (size_t)(k0 + kk) * HC + bn + bn4);
        }
        __syncthreads();
#pragma unroll
        for (int kk = 0; kk < 16; ++kk) {
            float a[8], b[8];
            *(float4*)&a[0] = *(const float4*)&As[kk][ty * 8];
            *(float4*)&a[4] = *(const float4*)&As[kk][ty * 8 + 4];
            *(float4*)&b[0] = *(const float4*)&Bs[kk][tx * 8];
            *(float4*)&b[4] = *(const float4*)&Bs[kk][tx * 8 + 4];
#pragma unroll
            for (int i = 0; i < 8; ++i)
#pragma unroll
                for (int j = 0; j < 8; ++j)
                    acc[i][j] = fmaf(a[i], b[j], acc[i][j]);
        }
        __syncthreads();
    }
    // C write (fp16, 8 halves = 16B per store)
#pragma unroll
    for (int i = 0; i < 8; ++i) {
        int row = bm + ty * 8 + i;
        if (row < M) {
            __half hv[8];
#pragma unroll
            for (int j = 0; j < 8; ++j) hv[j] = __float2half(acc[i][j]);
            *(uint4*)(C + (size_t)row * HC + bn + tx * 8) = *(uint4*)hv;
        }
    }
    // fused als/ald epilogue: head = (bn>>6) + (tx>>3), cols tx*8..tx*8+7
    const int ch0 = bn + tx * 8;
    float asv[8], adv[8];
#pragma unroll
    for (int j = 0; j < 8; ++j) { asv[j] = a_s[ch0 + j]; adv[j] = a_d[ch0 + j]; }
#pragma unroll
    for (int i = 0; i < 8; ++i) {
        int row = bm + ty * 8 + i;
        float ps = 0.f, pd = 0.f;
#pragma unroll
        for (int j = 0; j < 8; ++j) {
            ps = fmaf(acc[i][j], asv[j], ps);
            pd = fmaf(acc[i][j], adv[j], pd);
        }
#pragma unroll
        for (int d = 1; d < 8; d <<= 1) {  // reduce the 8 lanes of one head-half
            ps += __shfl_xor(ps, d, 64);
            pd += __shfl_xor(pd, d, 64);
        }
        if ((tx & 7) == 0 && row < M) {
            int head = (bn >> 6) + (tx >> 3);
            als[row * NH + head] = ps;
            ald[row * NH + head] = pd;
        }
    }
}

// ---------------- GAT aggregation: one wave per dst ----------------
// Chunk-parallel edge prep + pipelined fp16 h-row gather (8 rows in flight).
__global__ __launch_bounds__(256) void gat_edge_kernel(const __half* __restrict__ h,
                                                       const int* __restrict__ offs,
                                                       const int* __restrict__ ssrc,
                                                       const float* __restrict__ als,
                                                       const float* __restrict__ ald,
                                                       const float* __restrict__ bias,
                                                       float* __restrict__ out) {
    __shared__ float ex_sm[4][64][NH];
    __shared__ int   src_sm[4][64];
    const int lane = threadIdx.x & 63;
    const int w = threadIdx.x >> 6;
    const int v = (blockIdx.x << 2) + w;
    if (v >= N_NODES) return;
    const int hh = lane >> 4;
    const float4 aldv4 = *(const float4*)(ald + v * NH);
    const int beg = offs[v], end = offs[v + 1];  // degree >= 1 (self-loop)

    float4 m4 = make_float4(-INFINITY, -INFINITY, -INFINITY, -INFINITY);
    float4 s4 = make_float4(0.f, 0.f, 0.f, 0.f);
    float ax = 0.f, ay = 0.f, az = 0.f, aw = 0.f;

    for (int c0 = beg; c0 < end; c0 += 64) {
        const int n = min(64, end - c0);
        // ---- phase 1: lane-per-edge prep ----
        const int s0 = ssrc[c0];  // pad value for inactive lanes
        int srcl = s0;
        float4 e4 = make_float4(-INFINITY, -INFINITY, -INFINITY, -INFINITY);
        if (lane < n) {
            srcl = ssrc[c0 + lane];  // coalesced
            float4 a4 = *(const float4*)(als + srcl * NH);
            e4.x = lrelu(a4.x + aldv4.x);
            e4.y = lrelu(a4.y + aldv4.y);
            e4.z = lrelu(a4.z + aldv4.z);
            e4.w = lrelu(a4.w + aldv4.w);
        }
        // chunk max per head
        float4 cm = e4;
#pragma unroll
        for (int d = 1; d < 64; d <<= 1) {
            cm.x = fmaxf(cm.x, __shfl_xor(cm.x, d, 64));
            cm.y = fmaxf(cm.y, __shfl_xor(cm.y, d, 64));
            cm.z = fmaxf(cm.z, __shfl_xor(cm.z, d, 64));
            cm.w = fmaxf(cm.w, __shfl_xor(cm.w, d, 64));
        }
        const float4 mn = make_float4(fmaxf(m4.x, cm.x), fmaxf(m4.y, cm.y),
                                      fmaxf(m4.z, cm.z), fmaxf(m4.w, cm.w));
        const float4 r4 = make_float4(__expf(m4.x - mn.x), __expf(m4.y - mn.y),
                                      __expf(m4.z - mn.z), __expf(m4.w - mn.w));
        float4 ex4;  // 0 for inactive lanes (e = -inf, mn finite)
        ex4.x = __expf(e4.x - mn.x);
        ex4.y = __expf(e4.y - mn.y);
        ex4.z = __expf(e4.z - mn.z);
        ex4.w = __expf(e4.w - mn.w);
        src_sm[w][lane] = srcl;
        *(float4*)&ex_sm[w][lane][0] = ex4;
        // wave sum of ex per head
        float4 se = ex4;
#pragma unroll
        for (int d = 1; d < 64; d <<= 1) {
            se.x += __shfl_xor(se.x, d, 64);
            se.y += __shfl_xor(se.y, d, 64);
            se.z += __shfl_xor(se.z, d, 64);
            se.w += __shfl_xor(se.w, d, 64);
        }
        s4 = make_float4(fmaf(s4.x, r4.x, se.x), fmaf(s4.y, r4.y, se.y),
                         fmaf(s4.z, r4.z, se.z), fmaf(s4.w, r4.w, se.w));
        const float rh = hh == 0 ? r4.x : hh == 1 ? r4.y : hh == 2 ? r4.z : r4.w;
        ax *= rh; ay *= rh; az *= rh; aw *= rh;
        m4 = mn;

        // ---- phase 2: pipelined fp16 gather-accumulate (groups of 8) ----
        const int trip = (n + 7) & ~7;  // tail entries have weight 0 in LDS
        int sj[8]; float wj[8];
#pragma unroll
        for (int q = 0; q < 8; ++q) { sj[q] = src_sm[w][q]; wj[q] = ex_sm[w][q][hh]; }
        const int co = lane << 2;  // channel offset (halves)
        for (int j = 0; j < trip; j += 8) {
            uint2 raw[8];
#pragma unroll
            for (int q = 0; q < 8; ++q)
                raw[q] = *(const uint2*)(h + (size_t)sj[q] * HC + co);
            float u[8];
#pragma unroll
            for (int q = 0; q < 8; ++q) u[q] = wj[q];
            if (j + 8 < trip) {  // preload next group's (src, w) under load latency
#pragma unroll
                for (int q = 0; q < 8; ++q) {
                    sj[q] = src_sm[w][j + 8 + q];
                    wj[q] = ex_sm[w][j + 8 + q][hh];
                }
            }
#pragma unroll
            for (int q = 0; q < 8; ++q) {
                const __half2 lo = *reinterpret_cast<const __half2*>(&raw[q].x);
                const __half2 hi = *reinterpret_cast<const __half2*>(&raw[q].y);
                const float2 f0 = __half22float2(lo);
                const float2 f1 = __half22float2(hi);
                ax = fmaf(u[q], f0.x, ax); ay = fmaf(u[q], f0.y, ay);
                az = fmaf(u[q], f1.x, az); aw = fmaf(u[q], f1.y, aw);
            }
        }
    }

    const float sh = hh == 0 ? s4.x : hh == 1 ? s4.y : hh == 2 ? s4.z : s4.w;
    const float inv = 1.f / (sh + 1e-16f);
    const float4 b4 = *(const float4*)(bias + (lane << 2));
    *(float4*)(out + (size_t)v * HC + (lane << 2)) =
        make_float4(fmaf(ax, inv, b4.x), fmaf(ay, inv, b4.y),
                    fmaf(az, inv, b4.z), fmaf(aw, inv, b4.w));
}

// ---------------- BatchNorm stats (apply is fused into consumers) ----------------
__global__ __launch_bounds__(256) void bn_stats_kernel(const float* __restrict__ y,
                                                       double* __restrict__ sum,
                                                       double* __restrict__ sqsum) {
    const int t = threadIdx.x;  // channel
    const int r0 = blockIdx.x * 128;
    const int r1 = min(r0 + 128, N_NODES);
    float s = 0.f, q = 0.f;
    for (int r = r0; r < r1; ++r) {
        float v = y[(size_t)r * HC + t];
        s += v;
        q = fmaf(v, v, q);
    }
    atomicAdd(&sum[t], (double)s);
    atomicAdd(&sqsum[t], (double)q);
}

__global__ void bn_finalize_kernel(const double* __restrict__ sum,
                                   const double* __restrict__ sqsum,
                                   const float* __restrict__ g,
                                   const float* __restrict__ be,
                                   float* __restrict__ scale,
                                   float* __restrict__ shift) {
    int t = threadIdx.x;
    double mean = sum[t] / (double)N_NODES;
    double var = sqsum[t] / (double)N_NODES - mean * mean;
    float sc = g[t] * rsqrtf((float)var + 1e-5f);
    scale[t] = sc;
    shift[t] = be[t] - (float)mean * sc;
}

// ---------------- final linear: out[N,32] = relu(bn(y))[N,256] @ Wl[256,32] + bl ----
__global__ __launch_bounds__(256) void linear_kernel(const float* __restrict__ y,
                                                     const float* __restrict__ Wl,
                                                     const float* __restrict__ bl,
                                                     const float* __restrict__ scale,
                                                     const float* __restrict__ shift,
                                                     float* __restrict__ out) {
    __shared__ float Wls[256 * 32];
    __shared__ float scs[256], shs[256];
    const int t = threadIdx.x;
    for (int i = t; i < 256 * 32; i += 256) Wls[i] = Wl[i];
    scs[t] = scale[t];
    shs[t] = shift[t];
    __syncthreads();
    int gid = blockIdx.x * 256 + t;
    if (gid >= N_NODES * 32) return;
    int n = gid >> 5, j = gid & 31;
    float acc = bl[j];
    const float4* yrow = (const float4*)(y + (size_t)n * HC);
#pragma unroll
    for (int k4 = 0; k4 < 64; ++k4) {
        float4 y4 = yrow[k4];
        int k = k4 << 2;
        y4.x = fmaxf(0.f, fmaf(y4.x, scs[k + 0], shs[k + 0]));
        y4.y = fmaxf(0.f, fmaf(y4.y, scs[k + 1], shs[k + 1]));
        y4.z = fmaxf(0.f, fmaf(y4.z, scs[k + 2], shs[k + 2]));
        y4.w = fmaxf(0.f, fmaf(y4.w, scs[k + 3], shs[k + 3]));
        acc = fmaf(y4.x, Wls[(k + 0) * 32 + j], acc);
        acc = fmaf(y4.y, Wls[(k + 1) * 32 + j], acc);
        acc = fmaf(y4.z, Wls[(k + 2) * 32 + j], acc);
        acc = fmaf(y4.w, Wls[(k + 3) * 32 + j], acc);
    }
    out[gid] = acc;
}

extern "C" void kernel_launch(void* const* d_in, const int* in_sizes, int n_in,
                              void* d_out, int out_size, void* d_ws, size_t ws_size,
                              hipStream_t stream) {
    const float* x     = (const float*)d_in[0];
    const int* ei_sp   = (const int*)d_in[1];
    const int* ei_tp   = (const int*)d_in[2];
    const float* Wl    = (const float*)d_in[27];
    const float* bl    = (const float*)d_in[28];

    // ---- workspace layout ----
    char* ws = (char*)d_ws;
    size_t off = 0;
    auto alloc = [&](size_t bytes) -> char* {
        char* p = ws + off;
        off = (off + bytes + 255) & ~(size_t)255;
        return p;
    };
    __half* buf0   = (__half*)alloc((size_t)N_NODES * HC * 2);  // gemm output h (fp16)
    float* buf1    = (float*)alloc((size_t)N_NODES * HC * 4);   // gat output / next input
    float* als     = (float*)alloc((size_t)N_NODES * NH * 4);
    float* ald     = (float*)alloc((size_t)N_NODES * NH * 4);
    int*   offs_sp = (int*)alloc((size_t)(N_NODES + 1) * 4);
    int*   offs_tp = (int*)alloc((size_t)(N_NODES + 1) * 4);
    int*   src_sp  = (int*)alloc((size_t)TOT_E * 4);
    int*   src_tp  = (int*)alloc((size_t)TOT_E * 4);
    int*   cnt     = (int*)alloc((size_t)N_NODES * 4);
    int*   bsum    = (int*)alloc((size_t)SCAN_NB * 4);
    double* bnsum  = (double*)alloc(256 * 8 * 2);  // sum + sqsum contiguous
    double* bnsq   = bnsum + 256;
    float* scale   = (float*)alloc(256 * 4);
    float* shift   = (float*)alloc(256 * 4);
    (void)ws_size; (void)in_sizes; (void)n_in; (void)out_size;

    const int EB = (TOT_E + 255) / 256;

    // ---- build CSR for both edge types (once per call) ----
    hipMemsetAsync(cnt, 0, (size_t)N_NODES * 4, stream);
    count_kernel<<<EB, 256, 0, stream>>>(ei_sp, cnt);
    scan1_kernel<<<SCAN_NB, 256, 0, stream>>>(cnt, offs_sp, bsum);
    scan2_kernel<<<1, 256, 0, stream>>>(bsum, offs_sp + N_NODES);
    scan3_kernel<<<SCAN_NB, 256, 0, stream>>>(offs_sp, bsum);
    hipMemsetAsync(cnt, 0, (size_t)N_NODES * 4, stream);
    scatter_kernel<<<EB, 256, 0, stream>>>(ei_sp, offs_sp, cnt, src_sp);

    hipMemsetAsync(cnt, 0, (size_t)N_NODES * 4, stream);
    count_kernel<<<EB, 256, 0, stream>>>(ei_tp, cnt);
    scan1_kernel<<<SCAN_NB, 256, 0, stream>>>(cnt, offs_tp, bsum);
    scan2_kernel<<<1, 256, 0, stream>>>(bsum, offs_tp + N_NODES);
    scan3_kernel<<<SCAN_NB, 256, 0, stream>>>(offs_tp, bsum);
    hipMemsetAsync(cnt, 0, (size_t)N_NODES * 4, stream);
    scatter_kernel<<<EB, 256, 0, stream>>>(ei_tp, offs_tp, cnt, src_tp);

    // ---- 4 GAT + BN(+fused apply) layers ----
    const int NB4 = (N_NODES + 3) / 4;             // wave-per-node kernels
    const dim3 ggrid((N_NODES + 127) / 128, 2);    // gemm grid (128x128 tiles)
    for (int L = 0; L < 4; ++L) {
        const float* in = (L == 0) ? x : buf1;
        const int K = (L == 0) ? 128 : 256;
        const float* bns = (L == 0) ? nullptr : scale;  // prev layer's BN, fused
        const float* bnh = (L == 0) ? nullptr : shift;
        const int* offs = (L < 2) ? offs_sp : offs_tp;
        const int* ssrc = (L < 2) ? src_sp : src_tp;
        const int base = 3 + L * 6;
        const float* W  = (const float*)d_in[base + 0];
        const float* as_ = (const float*)d_in[base + 1];
        const float* ad_ = (const float*)d_in[base + 2];
        const float* b_  = (const float*)d_in[base + 3];
        const float* g_  = (const float*)d_in[base + 4];
        const float* be_ = (const float*)d_in[base + 5];

        gemm_kernel<<<ggrid, 256, 0, stream>>>(in, W, buf0, bns, bnh,
                                               as_, ad_, als, ald, N_NODES, K);
        gat_edge_kernel<<<NB4, 256, 0, stream>>>(buf0, offs, ssrc, als, ald, b_, buf1);

        hipMemsetAsync(bnsum, 0, 256 * 8 * 2, stream);
        bn_stats_kernel<<<(N_NODES + 127) / 128, 256, 0, stream>>>(buf1, bnsum, bnsq);
        bn_finalize_kernel<<<1, 256, 0, stream>>>(bnsum, bnsq, g_, be_, scale, shift);
    }

    // ---- final linear (fused relu(bn(.)) of layer 4) ----
    linear_kernel<<<(N_NODES * 32 + 255) / 256, 256, 0, stream>>>(buf1, Wl, bl,
                                                                  scale, shift,
                                                                  (float*)d_out);
}

// Round 8
// 1057.016 us; speedup vs baseline: 1.3480x; 1.1141x over previous
//
#include <hip/hip_runtime.h>
#include <hip/hip_bf16.h>
#include <hip/hip_fp16.h>
#include <math.h>

#define N_NODES 50000
#define N_EDGES 800000
#define NH 4
#define HC 256
#define TOT_E (N_EDGES + N_NODES)
#define SCAN_NB ((N_NODES + 255) / 256)

typedef __attribute__((ext_vector_type(8))) short short8;
typedef __attribute__((ext_vector_type(4))) float f32x4;

static __device__ __forceinline__ float lrelu(float x) { return x >= 0.f ? x : 0.2f * x; }

static __device__ __forceinline__ unsigned short bf16_rne(float x) {
    unsigned int u = __float_as_uint(x);
    u += 0x7fff + ((u >> 16) & 1);
    return (unsigned short)(u >> 16);
}

// ---------------- CSR build (counting sort by dst) ----------------
__global__ __launch_bounds__(256) void count_kernel(const int* __restrict__ ei,
                                                    int* __restrict__ cnt) {
    int i = blockIdx.x * blockDim.x + threadIdx.x;
    if (i >= TOT_E) return;
    int dst = (i < N_EDGES) ? ei[N_EDGES + i] : (i - N_EDGES);  // self-loops appended
    atomicAdd(&cnt[dst], 1);
}

__global__ __launch_bounds__(256) void scan1_kernel(const int* __restrict__ cnt,
                                                    int* __restrict__ offs,
                                                    int* __restrict__ bsum) {
    __shared__ int sm[256];
    const int t = threadIdx.x;
    const int base = blockIdx.x * 256;
    int v = (base + t < N_NODES) ? cnt[base + t] : 0;
    sm[t] = v;
    __syncthreads();
#pragma unroll
    for (int d = 1; d < 256; d <<= 1) {
        int add = (t >= d) ? sm[t - d] : 0;
        __syncthreads();
        sm[t] += add;
        __syncthreads();
    }
    if (base + t < N_NODES) offs[base + t] = sm[t] - v;  // local exclusive
    if (t == 255) bsum[blockIdx.x] = sm[255];
}

__global__ __launch_bounds__(256) void scan2_kernel(int* __restrict__ bsum,
                                                    int* __restrict__ total) {
    __shared__ int sm[256];
    const int t = threadIdx.x;
    int v = (t < SCAN_NB) ? bsum[t] : 0;
    sm[t] = v;
    __syncthreads();
#pragma unroll
    for (int d = 1; d < 256; d <<= 1) {
        int add = (t >= d) ? sm[t - d] : 0;
        __syncthreads();
        sm[t] += add;
        __syncthreads();
    }
    if (t < SCAN_NB) bsum[t] = sm[t] - v;  // exclusive block offsets
    if (t == 255) *total = sm[255];        // == TOT_E
}

__global__ __launch_bounds__(256) void scan3_kernel(int* __restrict__ offs,
                                                    const int* __restrict__ bsum) {
    int i = blockIdx.x * blockDim.x + threadIdx.x;
    if (i < N_NODES) offs[i] += bsum[i >> 8];
}

__global__ __launch_bounds__(256) void scatter_kernel(const int* __restrict__ ei,
                                                      const int* __restrict__ offs,
                                                      int* __restrict__ cursor,
                                                      int* __restrict__ ssrc) {
    int i = blockIdx.x * blockDim.x + threadIdx.x;
    if (i >= TOT_E) return;
    int src, dst;
    if (i < N_EDGES) { src = ei[i]; dst = ei[N_EDGES + i]; }
    else             { src = i - N_EDGES; dst = src; }
    int pos = offs[dst] + atomicAdd(&cursor[dst], 1);
    ssrc[pos] = src;
}

// ---------------- MFMA GEMM (bf16 3-product split ~ fp32 accuracy) ----------------
// C[M,256](fp16) = relu(bn(A))[M,K] @ B[K,256]; 128x128 tile, 4 waves (2x2),
// K-step 32, mfma_f32_16x16x32_bf16. Fused als/ald epilogue from f32 accs.
__global__ __launch_bounds__(256) void gemm_kernel(const float* __restrict__ A,
                                                   const float* __restrict__ B,
                                                   __half* __restrict__ C,
                                                   const float* __restrict__ bnscale,
                                                   const float* __restrict__ bnshift,
                                                   const float* __restrict__ a_s,
                                                   const float* __restrict__ a_d,
                                                   float* __restrict__ als,
                                                   float* __restrict__ ald,
                                                   int M, int K) {
    __shared__ unsigned short Ah[128][40], Al[128][40];  // [row][k], pad 40 (16B-aligned rows)
    __shared__ unsigned short Bh[128][40], Bl[128][40];  // [col][k]
    const int t = threadIdx.x;
    const int l = t & 63;
    const int w = t >> 6;
    const int wr = w >> 1, wc = w & 1;       // wave 2x2 -> 64x64 subtile
    const int fr = l & 15;                    // fragment row/col lane
    const int kg = (l >> 4) << 3;             // fragment k-group base (0,8,16,24)
    const int bm = blockIdx.x * 128;
    const int bn = blockIdx.y * 128;
    // staging maps
    const int ra = t >> 1, ka = (t & 1) << 4;       // A: row 0..127, k-base 0/16
    const int nb = (t & 31) << 2, kb = (t >> 5) << 2;  // B: col-base, k-base (4x4 block)

    f32x4 acc[4][4] = {};

    for (int k0 = 0; k0 < K; k0 += 32) {
        // ---- stage A (optional fused BN+ReLU), split bf16 hi/lo ----
        {
            const int row = bm + ra;
#pragma unroll
            for (int i = 0; i < 4; ++i) {
                const int kk = ka + 4 * i;
                float4 a4 = make_float4(0.f, 0.f, 0.f, 0.f);
                if (row < M) a4 = *(const float4*)(A + (size_t)row * K + k0 + kk);
                if (bnscale) {
                    float4 sc = *(const float4*)(bnscale + k0 + kk);
                    float4 sh = *(const float4*)(bnshift + k0 + kk);
                    a4.x = fmaxf(0.f, fmaf(a4.x, sc.x, sh.x));
                    a4.y = fmaxf(0.f, fmaf(a4.y, sc.y, sh.y));
                    a4.z = fmaxf(0.f, fmaf(a4.z, sc.z, sh.z));
                    a4.w = fmaxf(0.f, fmaf(a4.w, sc.w, sh.w));
                }
                unsigned short h[4], lo[4];
                float v[4] = {a4.x, a4.y, a4.z, a4.w};
#pragma unroll
                for (int q = 0; q < 4; ++q) {
                    h[q] = bf16_rne(v[q]);
                    float hf = __uint_as_float((unsigned int)h[q] << 16);
                    lo[q] = bf16_rne(v[q] - hf);
                }
                *(uint2*)&Ah[ra][kk] = *(uint2*)h;
                *(uint2*)&Al[ra][kk] = *(uint2*)lo;
            }
        }
        // ---- stage B (transpose to [col][k]), split bf16 hi/lo ----
        {
            float4 bv[4];
#pragma unroll
            for (int i = 0; i < 4; ++i)
                bv[i] = *(const float4*)(B + (size_t)(k0 + kb + i) * HC + bn + nb);
            // transpose 4x4: col c gets k kb..kb+3
#pragma unroll
            for (int c = 0; c < 4; ++c) {
                float v[4] = {c == 0 ? bv[0].x : c == 1 ? bv[0].y : c == 2 ? bv[0].z : bv[0].w,
                              c == 0 ? bv[1].x : c == 1 ? bv[1].y : c == 2 ? bv[1].z : bv[1].w,
                              c == 0 ? bv[2].x : c == 1 ? bv[2].y : c == 2 ? bv[2].z : bv[2].w,
                              c == 0 ? bv[3].x : c == 1 ? bv[3].y : c == 2 ? bv[3].z : bv[3].w};
                unsigned short h[4], lo[4];
#pragma unroll
                for (int q = 0; q < 4; ++q) {
                    h[q] = bf16_rne(v[q]);
                    float hf = __uint_as_float((unsigned int)h[q] << 16);
                    lo[q] = bf16_rne(v[q] - hf);
                }
                *(uint2*)&Bh[nb + c][kb] = *(uint2*)h;
                *(uint2*)&Bl[nb + c][kb] = *(uint2*)lo;
            }
        }
        __syncthreads();
        // ---- fragments + MFMA ----
        short8 ahf[4], alf[4], bhf[4], blf[4];
#pragma unroll
        for (int m = 0; m < 4; ++m) {
            ahf[m] = *(const short8*)&Ah[wr * 64 + m * 16 + fr][kg];
            alf[m] = *(const short8*)&Al[wr * 64 + m * 16 + fr][kg];
        }
#pragma unroll
        for (int n = 0; n < 4; ++n) {
            bhf[n] = *(const short8*)&Bh[wc * 64 + n * 16 + fr][kg];
            blf[n] = *(const short8*)&Bl[wc * 64 + n * 16 + fr][kg];
        }
#pragma unroll
        for (int m = 0; m < 4; ++m)
#pragma unroll
            for (int n = 0; n < 4; ++n) {
                acc[m][n] = __builtin_amdgcn_mfma_f32_16x16x32_bf16(ahf[m], bhf[n], acc[m][n], 0, 0, 0);
                acc[m][n] = __builtin_amdgcn_mfma_f32_16x16x32_bf16(ahf[m], blf[n], acc[m][n], 0, 0, 0);
                acc[m][n] = __builtin_amdgcn_mfma_f32_16x16x32_bf16(alf[m], bhf[n], acc[m][n], 0, 0, 0);
            }
        __syncthreads();
    }

    // ---- C write (fp16): D[row][col], col=lane&15, row=(lane>>4)*4+r ----
#pragma unroll
    for (int m = 0; m < 4; ++m) {
        const int row0 = bm + wr * 64 + m * 16 + ((l >> 4) << 2);
#pragma unroll
        for (int n = 0; n < 4; ++n) {
            const int col = bn + wc * 64 + n * 16 + fr;
#pragma unroll
            for (int r = 0; r < 4; ++r) {
                if (row0 + r < M)
                    C[(size_t)(row0 + r) * HC + col] = __float2half(acc[m][n][r]);
            }
        }
    }
    // ---- fused als/ald: this wave's 64 cols == one head (64 channels) ----
    const int hw = (bn >> 6) + wc;  // head index
    float asv[4], adv[4];
#pragma unroll
    for (int n = 0; n < 4; ++n) {
        const int col = bn + wc * 64 + n * 16 + fr;
        asv[n] = a_s[col];
        adv[n] = a_d[col];
    }
#pragma unroll
    for (int m = 0; m < 4; ++m) {
        const int row0 = bm + wr * 64 + m * 16 + ((l >> 4) << 2);
#pragma unroll
        for (int r = 0; r < 4; ++r) {
            float ps = 0.f, pd = 0.f;
#pragma unroll
            for (int n = 0; n < 4; ++n) {
                ps = fmaf(acc[m][n][r], asv[n], ps);
                pd = fmaf(acc[m][n][r], adv[n], pd);
            }
#pragma unroll
            for (int d = 1; d < 16; d <<= 1) {  // reduce over 16 col-lanes
                ps += __shfl_xor(ps, d, 64);
                pd += __shfl_xor(pd, d, 64);
            }
            if (fr == 0 && row0 + r < M) {
                als[(row0 + r) * NH + hw] = ps;
                ald[(row0 + r) * NH + hw] = pd;
            }
        }
    }
}

// ---------------- GAT aggregation: one wave per dst ----------------
// Chunk-parallel edge prep + pipelined fp16 h-row gather (8 rows in flight).
__global__ __launch_bounds__(256) void gat_edge_kernel(const __half* __restrict__ h,
                                                       const int* __restrict__ offs,
                                                       const int* __restrict__ ssrc,
                                                       const float* __restrict__ als,
                                                       const float* __restrict__ ald,
                                                       const float* __restrict__ bias,
                                                       float* __restrict__ out) {
    __shared__ float ex_sm[4][64][NH];
    __shared__ int   src_sm[4][64];
    const int lane = threadIdx.x & 63;
    const int w = threadIdx.x >> 6;
    const int v = (blockIdx.x << 2) + w;
    if (v >= N_NODES) return;
    const int hh = lane >> 4;
    const float4 aldv4 = *(const float4*)(ald + v * NH);
    const int beg = offs[v], end = offs[v + 1];  // degree >= 1 (self-loop)

    float4 m4 = make_float4(-INFINITY, -INFINITY, -INFINITY, -INFINITY);
    float4 s4 = make_float4(0.f, 0.f, 0.f, 0.f);
    float ax = 0.f, ay = 0.f, az = 0.f, aw = 0.f;

    for (int c0 = beg; c0 < end; c0 += 64) {
        const int n = min(64, end - c0);
        const int s0 = ssrc[c0];  // pad value for inactive lanes
        int srcl = s0;
        float4 e4 = make_float4(-INFINITY, -INFINITY, -INFINITY, -INFINITY);
        if (lane < n) {
            srcl = ssrc[c0 + lane];  // coalesced
            float4 a4 = *(const float4*)(als + srcl * NH);
            e4.x = lrelu(a4.x + aldv4.x);
            e4.y = lrelu(a4.y + aldv4.y);
            e4.z = lrelu(a4.z + aldv4.z);
            e4.w = lrelu(a4.w + aldv4.w);
        }
        float4 cm = e4;
#pragma unroll
        for (int d = 1; d < 64; d <<= 1) {
            cm.x = fmaxf(cm.x, __shfl_xor(cm.x, d, 64));
            cm.y = fmaxf(cm.y, __shfl_xor(cm.y, d, 64));
            cm.z = fmaxf(cm.z, __shfl_xor(cm.z, d, 64));
            cm.w = fmaxf(cm.w, __shfl_xor(cm.w, d, 64));
        }
        const float4 mn = make_float4(fmaxf(m4.x, cm.x), fmaxf(m4.y, cm.y),
                                      fmaxf(m4.z, cm.z), fmaxf(m4.w, cm.w));
        const float4 r4 = make_float4(__expf(m4.x - mn.x), __expf(m4.y - mn.y),
                                      __expf(m4.z - mn.z), __expf(m4.w - mn.w));
        float4 ex4;  // 0 for inactive lanes
        ex4.x = __expf(e4.x - mn.x);
        ex4.y = __expf(e4.y - mn.y);
        ex4.z = __expf(e4.z - mn.z);
        ex4.w = __expf(e4.w - mn.w);
        src_sm[w][lane] = srcl;
        *(float4*)&ex_sm[w][lane][0] = ex4;
        float4 se = ex4;
#pragma unroll
        for (int d = 1; d < 64; d <<= 1) {
            se.x += __shfl_xor(se.x, d, 64);
            se.y += __shfl_xor(se.y, d, 64);
            se.z += __shfl_xor(se.z, d, 64);
            se.w += __shfl_xor(se.w, d, 64);
        }
        s4 = make_float4(fmaf(s4.x, r4.x, se.x), fmaf(s4.y, r4.y, se.y),
                         fmaf(s4.z, r4.z, se.z), fmaf(s4.w, r4.w, se.w));
        const float rh = hh == 0 ? r4.x : hh == 1 ? r4.y : hh == 2 ? r4.z : r4.w;
        ax *= rh; ay *= rh; az *= rh; aw *= rh;
        m4 = mn;

        const int trip = (n + 7) & ~7;  // tail entries have weight 0 in LDS
        int sj[8]; float wj[8];
#pragma unroll
        for (int q = 0; q < 8; ++q) { sj[q] = src_sm[w][q]; wj[q] = ex_sm[w][q][hh]; }
        const int co = lane << 2;
        for (int j = 0; j < trip; j += 8) {
            uint2 raw[8];
#pragma unroll
            for (int q = 0; q < 8; ++q)
                raw[q] = *(const uint2*)(h + (size_t)sj[q] * HC + co);
            float u[8];
#pragma unroll
            for (int q = 0; q < 8; ++q) u[q] = wj[q];
            if (j + 8 < trip) {
#pragma unroll
                for (int q = 0; q < 8; ++q) {
                    sj[q] = src_sm[w][j + 8 + q];
                    wj[q] = ex_sm[w][j + 8 + q][hh];
                }
            }
#pragma unroll
            for (int q = 0; q < 8; ++q) {
                const __half2 lo = *reinterpret_cast<const __half2*>(&raw[q].x);
                const __half2 hi = *reinterpret_cast<const __half2*>(&raw[q].y);
                const float2 f0 = __half22float2(lo);
                const float2 f1 = __half22float2(hi);
                ax = fmaf(u[q], f0.x, ax); ay = fmaf(u[q], f0.y, ay);
                az = fmaf(u[q], f1.x, az); aw = fmaf(u[q], f1.y, aw);
            }
        }
    }

    const float sh = hh == 0 ? s4.x : hh == 1 ? s4.y : hh == 2 ? s4.z : s4.w;
    const float inv = 1.f / (sh + 1e-16f);
    const float4 b4 = *(const float4*)(bias + (lane << 2));
    *(float4*)(out + (size_t)v * HC + (lane << 2)) =
        make_float4(fmaf(ax, inv, b4.x), fmaf(ay, inv, b4.y),
                    fmaf(az, inv, b4.z), fmaf(aw, inv, b4.w));
}

// ---------------- BatchNorm stats (apply is fused into consumers) ----------------
__global__ __launch_bounds__(256) void bn_stats_kernel(const float* __restrict__ y,
                                                       double* __restrict__ sum,
                                                       double* __restrict__ sqsum) {
    const int t = threadIdx.x;  // channel
    const int r0 = blockIdx.x * 128;
    const int r1 = min(r0 + 128, N_NODES);
    float s = 0.f, q = 0.f;
    for (int r = r0; r < r1; ++r) {
        float v = y[(size_t)r * HC + t];
        s += v;
        q = fmaf(v, v, q);
    }
    atomicAdd(&sum[t], (double)s);
    atomicAdd(&sqsum[t], (double)q);
}

__global__ void bn_finalize_kernel(const double* __restrict__ sum,
                                   const double* __restrict__ sqsum,
                                   const float* __restrict__ g,
                                   const float* __restrict__ be,
                                   float* __restrict__ scale,
                                   float* __restrict__ shift) {
    int t = threadIdx.x;
    double mean = sum[t] / (double)N_NODES;
    double var = sqsum[t] / (double)N_NODES - mean * mean;
    float sc = g[t] * rsqrtf((float)var + 1e-5f);
    scale[t] = sc;
    shift[t] = be[t] - (float)mean * sc;
}

// ---------------- final linear: out[N,32] = relu(bn(y))[N,256] @ Wl[256,32] + bl ----
__global__ __launch_bounds__(256) void linear_kernel(const float* __restrict__ y,
                                                     const float* __restrict__ Wl,
                                                     const float* __restrict__ bl,
                                                     const float* __restrict__ scale,
                                                     const float* __restrict__ shift,
                                                     float* __restrict__ out) {
    __shared__ float Wls[256 * 32];
    __shared__ float scs[256], shs[256];
    const int t = threadIdx.x;
    for (int i = t; i < 256 * 32; i += 256) Wls[i] = Wl[i];
    scs[t] = scale[t];
    shs[t] = shift[t];
    __syncthreads();
    int gid = blockIdx.x * 256 + t;
    if (gid >= N_NODES * 32) return;
    int n = gid >> 5, j = gid & 31;
    float acc = bl[j];
    const float4* yrow = (const float4*)(y + (size_t)n * HC);
#pragma unroll
    for (int k4 = 0; k4 < 64; ++k4) {
        float4 y4 = yrow[k4];
        int k = k4 << 2;
        y4.x = fmaxf(0.f, fmaf(y4.x, scs[k + 0], shs[k + 0]));
        y4.y = fmaxf(0.f, fmaf(y4.y, scs[k + 1], shs[k + 1]));
        y4.z = fmaxf(0.f, fmaf(y4.z, scs[k + 2], shs[k + 2]));
        y4.w = fmaxf(0.f, fmaf(y4.w, scs[k + 3], shs[k + 3]));
        acc = fmaf(y4.x, Wls[(k + 0) * 32 + j], acc);
        acc = fmaf(y4.y, Wls[(k + 1) * 32 + j], acc);
        acc = fmaf(y4.z, Wls[(k + 2) * 32 + j], acc);
        acc = fmaf(y4.w, Wls[(k + 3) * 32 + j], acc);
    }
    out[gid] = acc;
}

extern "C" void kernel_launch(void* const* d_in, const int* in_sizes, int n_in,
                              void* d_out, int out_size, void* d_ws, size_t ws_size,
                              hipStream_t stream) {
    const float* x     = (const float*)d_in[0];
    const int* ei_sp   = (const int*)d_in[1];
    const int* ei_tp   = (const int*)d_in[2];
    const float* Wl    = (const float*)d_in[27];
    const float* bl    = (const float*)d_in[28];

    // ---- workspace layout ----
    char* ws = (char*)d_ws;
    size_t off = 0;
    auto alloc = [&](size_t bytes) -> char* {
        char* p = ws + off;
        off = (off + bytes + 255) & ~(size_t)255;
        return p;
    };
    __half* buf0   = (__half*)alloc((size_t)N_NODES * HC * 2);  // gemm output h (fp16)
    float* buf1    = (float*)alloc((size_t)N_NODES * HC * 4);   // gat output / next input
    float* als     = (float*)alloc((size_t)N_NODES * NH * 4);
    float* ald     = (float*)alloc((size_t)N_NODES * NH * 4);
    int*   offs_sp = (int*)alloc((size_t)(N_NODES + 1) * 4);
    int*   offs_tp = (int*)alloc((size_t)(N_NODES + 1) * 4);
    int*   src_sp  = (int*)alloc((size_t)TOT_E * 4);
    int*   src_tp  = (int*)alloc((size_t)TOT_E * 4);
    int*   cnt     = (int*)alloc((size_t)N_NODES * 4);
    int*   bsum    = (int*)alloc((size_t)SCAN_NB * 4);
    double* bnsum  = (double*)alloc(256 * 8 * 2);  // sum + sqsum contiguous
    double* bnsq   = bnsum + 256;
    float* scale   = (float*)alloc(256 * 4);
    float* shift   = (float*)alloc(256 * 4);
    (void)ws_size; (void)in_sizes; (void)n_in; (void)out_size;

    const int EB = (TOT_E + 255) / 256;

    // ---- build CSR for both edge types (once per call) ----
    hipMemsetAsync(cnt, 0, (size_t)N_NODES * 4, stream);
    count_kernel<<<EB, 256, 0, stream>>>(ei_sp, cnt);
    scan1_kernel<<<SCAN_NB, 256, 0, stream>>>(cnt, offs_sp, bsum);
    scan2_kernel<<<1, 256, 0, stream>>>(bsum, offs_sp + N_NODES);
    scan3_kernel<<<SCAN_NB, 256, 0, stream>>>(offs_sp, bsum);
    hipMemsetAsync(cnt, 0, (size_t)N_NODES * 4, stream);
    scatter_kernel<<<EB, 256, 0, stream>>>(ei_sp, offs_sp, cnt, src_sp);

    hipMemsetAsync(cnt, 0, (size_t)N_NODES * 4, stream);
    count_kernel<<<EB, 256, 0, stream>>>(ei_tp, cnt);
    scan1_kernel<<<SCAN_NB, 256, 0, stream>>>(cnt, offs_tp, bsum);
    scan2_kernel<<<1, 256, 0, stream>>>(bsum, offs_tp + N_NODES);
    scan3_kernel<<<SCAN_NB, 256, 0, stream>>>(offs_tp, bsum);
    hipMemsetAsync(cnt, 0, (size_t)N_NODES * 4, stream);
    scatter_kernel<<<EB, 256, 0, stream>>>(ei_tp, offs_tp, cnt, src_tp);

    // ---- 4 GAT + BN(+fused apply) layers ----
    const int NB4 = (N_NODES + 3) / 4;             // wave-per-node kernels
    const dim3 ggrid((N_NODES + 127) / 128, 2);    // gemm grid (128x128 tiles)
    for (int L = 0; L < 4; ++L) {
        const float* in = (L == 0) ? x : buf1;
        const int K = (L == 0) ? 128 : 256;
        const float* bns = (L == 0) ? nullptr : scale;  // prev layer's BN, fused
        const float* bnh = (L == 0) ? nullptr : shift;
        const int* offs = (L < 2) ? offs_sp : offs_tp;
        const int* ssrc = (L < 2) ? src_sp : src_tp;
        const int base = 3 + L * 6;
        const float* W  = (const float*)d_in[base + 0];
        const float* as_ = (const float*)d_in[base + 1];
        const float* ad_ = (const float*)d_in[base + 2];
        const float* b_  = (const float*)d_in[base + 3];
        const float* g_  = (const float*)d_in[base + 4];
        const float* be_ = (const float*)d_in[base + 5];

        gemm_kernel<<<ggrid, 256, 0, stream>>>(in, W, buf0, bns, bnh,
                                               as_, ad_, als, ald, N_NODES, K);
        gat_edge_kernel<<<NB4, 256, 0, stream>>>(buf0, offs, ssrc, als, ald, b_, buf1);

        hipMemsetAsync(bnsum, 0, 256 * 8 * 2, stream);
        bn_stats_kernel<<<(N_NODES + 127) / 128, 256, 0, stream>>>(buf1, bnsum, bnsq);
        bn_finalize_kernel<<<1, 256, 0, stream>>>(bnsum, bnsq, g_, be_, scale, shift);
    }

    // ---- final linear (fused relu(bn(.)) of layer 4) ----
    linear_kernel<<<(N_NODES * 32 + 255) / 256, 256, 0, stream>>>(buf1, Wl, bl,
                                                                  scale, shift,
                                                                  (float*)d_out);
}

// Round 9
// 1021.225 us; speedup vs baseline: 1.3952x; 1.0350x over previous
//
#include <hip/hip_runtime.h>
#include <hip/hip_bf16.h>
#include <hip/hip_fp16.h>
#include <math.h>

#define N_NODES 50000
#define N_EDGES 800000
#define NH 4
#define HC 256
#define TOT_E (N_EDGES + N_NODES)
#define NT2 (2 * N_NODES)
#define NB2 ((NT2 + 255) / 256)   // 391

typedef __attribute__((ext_vector_type(8))) short short8;
typedef __attribute__((ext_vector_type(4))) float f32x4;
typedef unsigned short ushort_t;

static __device__ __forceinline__ float lrelu(float x) { return x >= 0.f ? x : 0.2f * x; }

static __device__ __forceinline__ ushort_t bf16_rne(float x) {
    unsigned int u = __float_as_uint(x);
    u += 0x7fff + ((u >> 16) & 1);
    return (ushort_t)(u >> 16);
}

// ---------------- CSR build: both edge types in one pipeline ----------------
// index space: node d of type sp -> d ; type tp -> N_NODES + d
__global__ __launch_bounds__(256) void count2_kernel(const int* __restrict__ ei_sp,
                                                     const int* __restrict__ ei_tp,
                                                     int* __restrict__ cnt) {
    int i = blockIdx.x * blockDim.x + threadIdx.x;
    if (i >= 2 * TOT_E) return;
    int dst;
    if (i < TOT_E) dst = (i < N_EDGES) ? ei_sp[N_EDGES + i] : (i - N_EDGES);
    else {
        int j = i - TOT_E;
        dst = N_NODES + ((j < N_EDGES) ? ei_tp[N_EDGES + j] : (j - N_EDGES));
    }
    atomicAdd(&cnt[dst], 1);
}

__global__ __launch_bounds__(256) void scan1_kernel(const int* __restrict__ cnt,
                                                    int* __restrict__ offs,
                                                    int* __restrict__ bsum) {
    __shared__ int sm[256];
    const int t = threadIdx.x;
    const int base = blockIdx.x * 256;
    int v = (base + t < NT2) ? cnt[base + t] : 0;
    sm[t] = v;
    __syncthreads();
#pragma unroll
    for (int d = 1; d < 256; d <<= 1) {
        int add = (t >= d) ? sm[t - d] : 0;
        __syncthreads();
        sm[t] += add;
        __syncthreads();
    }
    if (base + t < NT2) offs[base + t] = sm[t] - v;  // local exclusive
    if (t == 255) bsum[blockIdx.x] = sm[255];
}

__global__ __launch_bounds__(512) void scan2_kernel(int* __restrict__ bsum,
                                                    int* __restrict__ total) {
    __shared__ int sm[512];
    const int t = threadIdx.x;
    int v = (t < NB2) ? bsum[t] : 0;
    sm[t] = v;
    __syncthreads();
#pragma unroll
    for (int d = 1; d < 512; d <<= 1) {
        int add = (t >= d) ? sm[t - d] : 0;
        __syncthreads();
        sm[t] += add;
        __syncthreads();
    }
    if (t < NB2) bsum[t] = sm[t] - v;
    if (t == 511) *total = sm[511];  // == 2*TOT_E
}

__global__ __launch_bounds__(256) void scan3_kernel(int* __restrict__ offs,
                                                    const int* __restrict__ bsum) {
    int i = blockIdx.x * blockDim.x + threadIdx.x;
    if (i < NT2) offs[i] += bsum[i >> 8];
}

__global__ __launch_bounds__(256) void scatter2_kernel(const int* __restrict__ ei_sp,
                                                       const int* __restrict__ ei_tp,
                                                       const int* __restrict__ offs,
                                                       int* __restrict__ cursor,
                                                       int* __restrict__ ssrc) {
    int i = blockIdx.x * blockDim.x + threadIdx.x;
    if (i >= 2 * TOT_E) return;
    int src, dstIdx;
    if (i < TOT_E) {
        src = (i < N_EDGES) ? ei_sp[i] : (i - N_EDGES);
        dstIdx = (i < N_EDGES) ? ei_sp[N_EDGES + i] : (i - N_EDGES);
    } else {
        int j = i - TOT_E;
        src = (j < N_EDGES) ? ei_tp[j] : (j - N_EDGES);
        dstIdx = N_NODES + ((j < N_EDGES) ? ei_tp[N_EDGES + j] : (j - N_EDGES));
    }
    int pos = offs[dstIdx] + atomicAdd(&cursor[dstIdx], 1);
    ssrc[pos] = src;
}

// ---------------- pre-split passes (bf16 hi/lo, math identical to R8) ----------------
__global__ __launch_bounds__(256) void split_x_kernel(const float* __restrict__ x,
                                                      ushort_t* __restrict__ Ah,
                                                      ushort_t* __restrict__ Al) {
    int i = blockIdx.x * 256 + threadIdx.x;  // over N*32 float4s (K=128)
    float4 v = ((const float4*)x)[i];
    float a[4] = {v.x, v.y, v.z, v.w};
    ushort_t h[4], lo[4];
#pragma unroll
    for (int q = 0; q < 4; ++q) {
        h[q] = bf16_rne(a[q]);
        float hf = __uint_as_float((unsigned int)h[q] << 16);
        lo[q] = bf16_rne(a[q] - hf);
    }
    *(uint2*)(Ah + (size_t)i * 4) = *(uint2*)h;
    *(uint2*)(Al + (size_t)i * 4) = *(uint2*)lo;
}

// BN(scale/shift from bnsum) + ReLU + split, for layer inputs 2..4
__global__ __launch_bounds__(256) void split_h_kernel(const float* __restrict__ y,
                                                      const double* __restrict__ sum,
                                                      const double* __restrict__ sqsum,
                                                      const float* __restrict__ g,
                                                      const float* __restrict__ be,
                                                      ushort_t* __restrict__ Ah,
                                                      ushort_t* __restrict__ Al) {
    __shared__ float scs[256], shs[256];
    const int t = threadIdx.x;
    {
        double mean = sum[t] / (double)N_NODES;
        double var = sqsum[t] / (double)N_NODES - mean * mean;
        float sc = g[t] * rsqrtf((float)var + 1e-5f);
        scs[t] = sc;
        shs[t] = be[t] - (float)mean * sc;
    }
    __syncthreads();
    int i = blockIdx.x * 256 + t;  // over N*64 float4s (exact)
    int c4 = (i & 63) << 2;
    float4 v = ((const float4*)y)[i];
    float a[4] = {fmaxf(0.f, fmaf(v.x, scs[c4 + 0], shs[c4 + 0])),
                  fmaxf(0.f, fmaf(v.y, scs[c4 + 1], shs[c4 + 1])),
                  fmaxf(0.f, fmaf(v.z, scs[c4 + 2], shs[c4 + 2])),
                  fmaxf(0.f, fmaf(v.w, scs[c4 + 3], shs[c4 + 3]))};
    ushort_t h[4], lo[4];
#pragma unroll
    for (int q = 0; q < 4; ++q) {
        h[q] = bf16_rne(a[q]);
        float hf = __uint_as_float((unsigned int)h[q] << 16);
        lo[q] = bf16_rne(a[q] - hf);
    }
    *(uint2*)(Ah + (size_t)i * 4) = *(uint2*)h;
    *(uint2*)(Al + (size_t)i * 4) = *(uint2*)lo;
}

// all 4 weight matrices -> col-major [256][K] bf16 hi/lo, output-coalesced
__global__ __launch_bounds__(256) void split_ball_kernel(const float* __restrict__ W1,
                                                         const float* __restrict__ W2,
                                                         const float* __restrict__ W3,
                                                         const float* __restrict__ W4,
                                                         ushort_t* __restrict__ Bh,
                                                         ushort_t* __restrict__ Bl) {
    int i = blockIdx.x * 256 + threadIdx.x;  // over 229376 (exact: 896 blocks)
    int loc, kshift;
    const float* W;
    if (i < 32768) { W = W1; loc = i; kshift = 7; }
    else {
        int L = (i - 32768) >> 16;
        W = L == 0 ? W2 : L == 1 ? W3 : W4;
        loc = (i - 32768) & 65535;
        kshift = 8;
    }
    int c = loc >> kshift, kl = loc & ((1 << kshift) - 1);
    float v = W[(size_t)kl * 256 + c];
    ushort_t h = bf16_rne(v);
    float hf = __uint_as_float((unsigned int)h << 16);
    Bh[i] = h;
    Bl[i] = bf16_rne(v - hf);
}

// ---------------- MFMA GEMM (pre-split bf16 inputs, 3-product ~fp32) ----------------
__global__ __launch_bounds__(256) void gemm_kernel(const ushort_t* __restrict__ Ahg,
                                                   const ushort_t* __restrict__ Alg,
                                                   const ushort_t* __restrict__ Bhg,
                                                   const ushort_t* __restrict__ Blg,
                                                   __half* __restrict__ C,
                                                   const float* __restrict__ a_s,
                                                   const float* __restrict__ a_d,
                                                   float* __restrict__ als,
                                                   float* __restrict__ ald,
                                                   int M, int K) {
    __shared__ ushort_t Ah[128][40], Al[128][40];  // pad 40 (80B rows, 16B-aligned)
    __shared__ ushort_t Bh[128][40], Bl[128][40];
    const int t = threadIdx.x;
    const int l = t & 63;
    const int w = t >> 6;
    const int wr = w >> 1, wc = w & 1;
    const int fr = l & 15;
    const int kg = (l >> 4) << 3;
    const int bm = blockIdx.x * 128;
    const int bn = blockIdx.y * 128;
    const int sr = t >> 1;          // staging row (A) / col (B): 0..127
    const int sk = (t & 1) << 4;    // k-base 0 / 16

    f32x4 acc[4][4] = {};

    for (int k0 = 0; k0 < K; k0 += 32) {
        const size_t abase = (size_t)(bm + sr) * K + k0 + sk;
        uint4 a0 = {}, a1 = {}, l0 = {}, l1 = {};
        if (bm + sr < M) {
            a0 = *(const uint4*)(Ahg + abase);
            a1 = *(const uint4*)(Ahg + abase + 8);
            l0 = *(const uint4*)(Alg + abase);
            l1 = *(const uint4*)(Alg + abase + 8);
        }
        const size_t bbase = (size_t)(bn + sr) * K + k0 + sk;
        uint4 b0 = *(const uint4*)(Bhg + bbase);
        uint4 b1 = *(const uint4*)(Bhg + bbase + 8);
        uint4 c0 = *(const uint4*)(Blg + bbase);
        uint4 c1 = *(const uint4*)(Blg + bbase + 8);
        *(uint4*)&Ah[sr][sk] = a0; *(uint4*)&Ah[sr][sk + 8] = a1;
        *(uint4*)&Al[sr][sk] = l0; *(uint4*)&Al[sr][sk + 8] = l1;
        *(uint4*)&Bh[sr][sk] = b0; *(uint4*)&Bh[sr][sk + 8] = b1;
        *(uint4*)&Bl[sr][sk] = c0; *(uint4*)&Bl[sr][sk + 8] = c1;
        __syncthreads();

        short8 ahf[4], alf[4], bhf[4], blf[4];
#pragma unroll
        for (int m = 0; m < 4; ++m) {
            ahf[m] = *(const short8*)&Ah[wr * 64 + m * 16 + fr][kg];
            alf[m] = *(const short8*)&Al[wr * 64 + m * 16 + fr][kg];
        }
#pragma unroll
        for (int n = 0; n < 4; ++n) {
            bhf[n] = *(const short8*)&Bh[wc * 64 + n * 16 + fr][kg];
            blf[n] = *(const short8*)&Bl[wc * 64 + n * 16 + fr][kg];
        }
#pragma unroll
        for (int m = 0; m < 4; ++m)
#pragma unroll
            for (int n = 0; n < 4; ++n) {
                acc[m][n] = __builtin_amdgcn_mfma_f32_16x16x32_bf16(ahf[m], bhf[n], acc[m][n], 0, 0, 0);
                acc[m][n] = __builtin_amdgcn_mfma_f32_16x16x32_bf16(ahf[m], blf[n], acc[m][n], 0, 0, 0);
                acc[m][n] = __builtin_amdgcn_mfma_f32_16x16x32_bf16(alf[m], bhf[n], acc[m][n], 0, 0, 0);
            }
        __syncthreads();
    }

    // C write (fp16): col=lane&15, row=(lane>>4)*4+r  [m89-verified layout]
#pragma unroll
    for (int m = 0; m < 4; ++m) {
        const int row0 = bm + wr * 64 + m * 16 + ((l >> 4) << 2);
#pragma unroll
        for (int n = 0; n < 4; ++n) {
            const int col = bn + wc * 64 + n * 16 + fr;
#pragma unroll
            for (int r = 0; r < 4; ++r) {
                if (row0 + r < M)
                    C[(size_t)(row0 + r) * HC + col] = __float2half(acc[m][n][r]);
            }
        }
    }
    // fused als/ald epilogue: this wave's 64 cols == one head
    const int hw = (bn >> 6) + wc;
    float asv[4], adv[4];
#pragma unroll
    for (int n = 0; n < 4; ++n) {
        const int col = bn + wc * 64 + n * 16 + fr;
        asv[n] = a_s[col];
        adv[n] = a_d[col];
    }
#pragma unroll
    for (int m = 0; m < 4; ++m) {
        const int row0 = bm + wr * 64 + m * 16 + ((l >> 4) << 2);
#pragma unroll
        for (int r = 0; r < 4; ++r) {
            float ps = 0.f, pd = 0.f;
#pragma unroll
            for (int n = 0; n < 4; ++n) {
                ps = fmaf(acc[m][n][r], asv[n], ps);
                pd = fmaf(acc[m][n][r], adv[n], pd);
            }
#pragma unroll
            for (int d = 1; d < 16; d <<= 1) {
                ps += __shfl_xor(ps, d, 64);
                pd += __shfl_xor(pd, d, 64);
            }
            if (fr == 0 && row0 + r < M) {
                als[(row0 + r) * NH + hw] = ps;
                ald[(row0 + r) * NH + hw] = pd;
            }
        }
    }
}

// ---------------- GAT aggregation: one wave per dst ----------------
// phase 1: lane-per-edge logits; phase 2: 16B/lane gather, 2 edges per load,
// half-waves combined by shfl_xor(32). Per-lane running sum, reduced once.
__global__ __launch_bounds__(256) void gat_edge_kernel(const __half* __restrict__ h,
                                                       const int* __restrict__ offs,
                                                       const int* __restrict__ ssrc,
                                                       const float* __restrict__ als,
                                                       const float* __restrict__ ald,
                                                       const float* __restrict__ bias,
                                                       float* __restrict__ out) {
    __shared__ float ex_sm[4][64][NH];
    __shared__ int   src_sm[4][64];
    const int lane = threadIdx.x & 63;
    const int w = threadIdx.x >> 6;
    const int v = (blockIdx.x << 2) + w;
    const int ehalf = lane >> 5;      // 0: even edges, 1: odd edges
    const int cl = lane & 31;         // channels 8*cl .. 8*cl+7
    const int hh2 = cl >> 3;          // accumulation head
    const float4 aldv4 = *(const float4*)(ald + v * NH);
    const int beg = offs[v], end = offs[v + 1];  // degree >= 1 (self-loop)

    float4 m4 = make_float4(-INFINITY, -INFINITY, -INFINITY, -INFINITY);
    float4 s4 = make_float4(0.f, 0.f, 0.f, 0.f);
    float acc8[8] = {0.f};

    for (int c0 = beg; c0 < end; c0 += 64) {
        const int n = min(64, end - c0);
        // ---- phase 1: lane-per-edge ----
        int srcl = ssrc[c0];
        float4 e4 = make_float4(-INFINITY, -INFINITY, -INFINITY, -INFINITY);
        if (lane < n) {
            srcl = ssrc[c0 + lane];
            float4 a4 = *(const float4*)(als + srcl * NH);
            e4.x = lrelu(a4.x + aldv4.x);
            e4.y = lrelu(a4.y + aldv4.y);
            e4.z = lrelu(a4.z + aldv4.z);
            e4.w = lrelu(a4.w + aldv4.w);
        }
        float4 cm = e4;
#pragma unroll
        for (int d = 1; d < 64; d <<= 1) {
            cm.x = fmaxf(cm.x, __shfl_xor(cm.x, d, 64));
            cm.y = fmaxf(cm.y, __shfl_xor(cm.y, d, 64));
            cm.z = fmaxf(cm.z, __shfl_xor(cm.z, d, 64));
            cm.w = fmaxf(cm.w, __shfl_xor(cm.w, d, 64));
        }
        const float4 mn = make_float4(fmaxf(m4.x, cm.x), fmaxf(m4.y, cm.y),
                                      fmaxf(m4.z, cm.z), fmaxf(m4.w, cm.w));
        const float4 r4 = make_float4(__expf(m4.x - mn.x), __expf(m4.y - mn.y),
                                      __expf(m4.z - mn.z), __expf(m4.w - mn.w));
        float4 ex4;  // 0 for inactive lanes
        ex4.x = __expf(e4.x - mn.x);
        ex4.y = __expf(e4.y - mn.y);
        ex4.z = __expf(e4.z - mn.z);
        ex4.w = __expf(e4.w - mn.w);
        src_sm[w][lane] = srcl;
        *(float4*)&ex_sm[w][lane][0] = ex4;
        s4 = make_float4(fmaf(s4.x, r4.x, ex4.x), fmaf(s4.y, r4.y, ex4.y),
                         fmaf(s4.z, r4.z, ex4.z), fmaf(s4.w, r4.w, ex4.w));
        const float rh2 = hh2 == 0 ? r4.x : hh2 == 1 ? r4.y : hh2 == 2 ? r4.z : r4.w;
#pragma unroll
        for (int i = 0; i < 8; ++i) acc8[i] *= rh2;
        m4 = mn;

        // ---- phase 2: 16B/lane gather (2 edges per load instruction) ----
        const int trip = (n + 7) & ~7;  // padded entries have weight 0
        const int co2 = cl << 3;        // fp16 channel offset
        for (int j = 0; j < trip; j += 8) {
            uint4 raw[4];
            float u[4];
#pragma unroll
            for (int q = 0; q < 4; ++q) {
                const int e = j + 2 * q + ehalf;
                const int s = src_sm[w][e];
                raw[q] = *(const uint4*)(h + (size_t)s * HC + co2);
                u[q] = ex_sm[w][e][hh2];
            }
#pragma unroll
            for (int q = 0; q < 4; ++q) {
                const __half2* p = reinterpret_cast<const __half2*>(&raw[q]);
#pragma unroll
                for (int z = 0; z < 4; ++z) {
                    const float2 f = __half22float2(p[z]);
                    acc8[2 * z]     = fmaf(u[q], f.x, acc8[2 * z]);
                    acc8[2 * z + 1] = fmaf(u[q], f.y, acc8[2 * z + 1]);
                }
            }
        }
    }

    // combine the two half-waves (lane l and l^32 hold the same channels)
#pragma unroll
    for (int i = 0; i < 8; ++i) acc8[i] += __shfl_xor(acc8[i], 32, 64);
    // reduce the per-lane softmax denominators
#pragma unroll
    for (int d = 1; d < 64; d <<= 1) {
        s4.x += __shfl_xor(s4.x, d, 64);
        s4.y += __shfl_xor(s4.y, d, 64);
        s4.z += __shfl_xor(s4.z, d, 64);
        s4.w += __shfl_xor(s4.w, d, 64);
    }
    const float sh = hh2 == 0 ? s4.x : hh2 == 1 ? s4.y : hh2 == 2 ? s4.z : s4.w;
    const float inv = 1.f / (sh + 1e-16f);
    if (ehalf == 0) {
        const int cb = cl << 3;
        const float4 b0 = *(const float4*)(bias + cb);
        const float4 b1 = *(const float4*)(bias + cb + 4);
        *(float4*)(out + (size_t)v * HC + cb) =
            make_float4(fmaf(acc8[0], inv, b0.x), fmaf(acc8[1], inv, b0.y),
                        fmaf(acc8[2], inv, b0.z), fmaf(acc8[3], inv, b0.w));
        *(float4*)(out + (size_t)v * HC + cb + 4) =
            make_float4(fmaf(acc8[4], inv, b1.x), fmaf(acc8[5], inv, b1.y),
                        fmaf(acc8[6], inv, b1.z), fmaf(acc8[7], inv, b1.w));
    }
}

// ---------------- BatchNorm stats ----------------
__global__ __launch_bounds__(256) void bn_stats_kernel(const float* __restrict__ y,
                                                       double* __restrict__ sum,
                                                       double* __restrict__ sqsum) {
    const int t = threadIdx.x;
    const int r0 = blockIdx.x * 128;
    const int r1 = min(r0 + 128, N_NODES);
    float s = 0.f, q = 0.f;
    for (int r = r0; r < r1; ++r) {
        float v = y[(size_t)r * HC + t];
        s += v;
        q = fmaf(v, v, q);
    }
    atomicAdd(&sum[t], (double)s);
    atomicAdd(&sqsum[t], (double)q);
}

// ---------------- final linear (BN from bnsum computed in-block) ----------------
__global__ __launch_bounds__(256) void linear_kernel(const float* __restrict__ y,
                                                     const float* __restrict__ Wl,
                                                     const float* __restrict__ bl,
                                                     const double* __restrict__ sum,
                                                     const double* __restrict__ sqsum,
                                                     const float* __restrict__ g,
                                                     const float* __restrict__ be,
                                                     float* __restrict__ out) {
    __shared__ float Wls[256 * 32];
    __shared__ float scs[256], shs[256];
    const int t = threadIdx.x;
    {
        double mean = sum[t] / (double)N_NODES;
        double var = sqsum[t] / (double)N_NODES - mean * mean;
        float sc = g[t] * rsqrtf((float)var + 1e-5f);
        scs[t] = sc;
        shs[t] = be[t] - (float)mean * sc;
    }
    for (int i = t; i < 256 * 32; i += 256) Wls[i] = Wl[i];
    __syncthreads();
    int gid = blockIdx.x * 256 + t;
    int n = gid >> 5, j = gid & 31;
    float acc = bl[j];
    const float4* yrow = (const float4*)(y + (size_t)n * HC);
#pragma unroll
    for (int k4 = 0; k4 < 64; ++k4) {
        float4 y4 = yrow[k4];
        int k = k4 << 2;
        y4.x = fmaxf(0.f, fmaf(y4.x, scs[k + 0], shs[k + 0]));
        y4.y = fmaxf(0.f, fmaf(y4.y, scs[k + 1], shs[k + 1]));
        y4.z = fmaxf(0.f, fmaf(y4.z, scs[k + 2], shs[k + 2]));
        y4.w = fmaxf(0.f, fmaf(y4.w, scs[k + 3], shs[k + 3]));
        acc = fmaf(y4.x, Wls[(k + 0) * 32 + j], acc);
        acc = fmaf(y4.y, Wls[(k + 1) * 32 + j], acc);
        acc = fmaf(y4.z, Wls[(k + 2) * 32 + j], acc);
        acc = fmaf(y4.w, Wls[(k + 3) * 32 + j], acc);
    }
    out[gid] = acc;
}

extern "C" void kernel_launch(void* const* d_in, const int* in_sizes, int n_in,
                              void* d_out, int out_size, void* d_ws, size_t ws_size,
                              hipStream_t stream) {
    const float* x   = (const float*)d_in[0];
    const int* ei_sp = (const int*)d_in[1];
    const int* ei_tp = (const int*)d_in[2];
    const float* Wl  = (const float*)d_in[27];
    const float* bl  = (const float*)d_in[28];

    char* ws = (char*)d_ws;
    size_t off = 0;
    auto alloc = [&](size_t bytes) -> char* {
        char* p = ws + off;
        off = (off + bytes + 255) & ~(size_t)255;
        return p;
    };
    ushort_t* AhA  = (ushort_t*)alloc((size_t)N_NODES * HC * 2);   // 25.6 MB
    ushort_t* AlA  = (ushort_t*)alloc((size_t)N_NODES * HC * 2);   // 25.6 MB
    __half* buf0   = (__half*)alloc((size_t)N_NODES * HC * 2);     // gemm out h (fp16)
    float* buf1    = (float*)alloc((size_t)N_NODES * HC * 4);      // gat out (fp32)
    float* als     = (float*)alloc((size_t)N_NODES * NH * 4);
    float* ald     = (float*)alloc((size_t)N_NODES * NH * 4);
    int*  offs_all = (int*)alloc((size_t)(NT2 + 1) * 4);
    int*  ssrc_all = (int*)alloc((size_t)2 * TOT_E * 4);
    int*  cnt_all  = (int*)alloc((size_t)2 * NT2 * 4);             // cnt + cursor
    int*  cursor   = cnt_all + NT2;
    int*  bsum     = (int*)alloc((size_t)NB2 * 4);
    ushort_t* BhA  = (ushort_t*)alloc((size_t)229376 * 2);
    ushort_t* BlA  = (ushort_t*)alloc((size_t)229376 * 2);
    double* bnsum  = (double*)alloc(256 * 8 * 2);
    double* bnsq   = bnsum + 256;
    (void)ws_size; (void)in_sizes; (void)n_in; (void)out_size;

    const int EB2 = (2 * TOT_E + 255) / 256;
    const int offB[4] = {0, 32768, 98304, 163840};

    // ---- CSR for both edge types, one pipeline ----
    hipMemsetAsync(cnt_all, 0, (size_t)2 * NT2 * 4, stream);
    count2_kernel<<<EB2, 256, 0, stream>>>(ei_sp, ei_tp, cnt_all);
    scan1_kernel<<<NB2, 256, 0, stream>>>(cnt_all, offs_all, bsum);
    scan2_kernel<<<1, 512, 0, stream>>>(bsum, offs_all + NT2);
    scan3_kernel<<<NB2, 256, 0, stream>>>(offs_all, bsum);
    scatter2_kernel<<<EB2, 256, 0, stream>>>(ei_sp, ei_tp, offs_all, cursor, ssrc_all);

    // ---- one-time splits ----
    split_x_kernel<<<N_NODES * 32 / 256, 256, 0, stream>>>(x, AhA, AlA);
    split_ball_kernel<<<896, 256, 0, stream>>>((const float*)d_in[3], (const float*)d_in[9],
                                               (const float*)d_in[15], (const float*)d_in[21],
                                               BhA, BlA);

    // ---- 4 GAT layers ----
    const int NB4 = N_NODES / 4;                 // 12500
    const dim3 ggrid((N_NODES + 127) / 128, 2);  // 391 x 2
    for (int L = 0; L < 4; ++L) {
        const int K = (L == 0) ? 128 : 256;
        const int* offs = (L < 2) ? offs_all : (offs_all + N_NODES);
        const int base = 3 + L * 6;
        const float* as_ = (const float*)d_in[base + 1];
        const float* ad_ = (const float*)d_in[base + 2];
        const float* b_  = (const float*)d_in[base + 3];

        if (L > 0) {
            const int pbase = 3 + (L - 1) * 6;
            split_h_kernel<<<N_NODES * 64 / 256, 256, 0, stream>>>(
                buf1, bnsum, bnsq, (const float*)d_in[pbase + 4],
                (const float*)d_in[pbase + 5], AhA, AlA);
        }
        gemm_kernel<<<ggrid, 256, 0, stream>>>(AhA, AlA, BhA + offB[L], BlA + offB[L],
                                               buf0, as_, ad_, als, ald, N_NODES, K);
        gat_edge_kernel<<<NB4, 256, 0, stream>>>(buf0, offs, ssrc_all, als, ald, b_, buf1);

        hipMemsetAsync(bnsum, 0, 256 * 8 * 2, stream);
        bn_stats_kernel<<<(N_NODES + 127) / 128, 256, 0, stream>>>(buf1, bnsum, bnsq);
    }

    // ---- final linear (fused relu(bn(.)) of layer 4) ----
    linear_kernel<<<N_NODES * 32 / 256, 256, 0, stream>>>(
        buf1, Wl, bl, bnsum, bnsq, (const float*)d_in[25], (const float*)d_in[26],
        (float*)d_out);
}

// Round 10
// 950.514 us; speedup vs baseline: 1.4990x; 1.0744x over previous
//
#include <hip/hip_runtime.h>
#include <hip/hip_bf16.h>
#include <hip/hip_fp16.h>
#include <math.h>

#define N_NODES 50000
#define N_EDGES 800000
#define NH 4
#define HC 256
#define TOT_E (N_EDGES + N_NODES)
#define NT2 (2 * N_NODES)
#define NB2 ((NT2 + 255) / 256)   // 391

typedef __attribute__((ext_vector_type(8))) short short8;
typedef __attribute__((ext_vector_type(4))) float f32x4;
typedef unsigned short ushort_t;

static __device__ __forceinline__ float lrelu(float x) { return x >= 0.f ? x : 0.2f * x; }

static __device__ __forceinline__ ushort_t bf16_rne(float x) {
    unsigned int u = __float_as_uint(x);
    u += 0x7fff + ((u >> 16) & 1);
    return (ushort_t)(u >> 16);
}

// ---------------- CSR build: both edge types, single-atomic ----------------
// index space: node d of type sp -> d ; type tp -> N_NODES + d
__global__ __launch_bounds__(256) void count2_kernel(const int* __restrict__ ei_sp,
                                                     const int* __restrict__ ei_tp,
                                                     int* __restrict__ cnt,
                                                     int* __restrict__ pos) {
    int i = blockIdx.x * blockDim.x + threadIdx.x;
    if (i >= 2 * TOT_E) return;
    int dst;
    if (i < TOT_E) dst = (i < N_EDGES) ? ei_sp[N_EDGES + i] : (i - N_EDGES);
    else {
        int j = i - TOT_E;
        dst = N_NODES + ((j < N_EDGES) ? ei_tp[N_EDGES + j] : (j - N_EDGES));
    }
    pos[i] = atomicAdd(&cnt[dst], 1);  // coalesced write of bucket position
}

__global__ __launch_bounds__(256) void scan1_kernel(const int* __restrict__ cnt,
                                                    int* __restrict__ offs,
                                                    int* __restrict__ bsum) {
    __shared__ int sm[256];
    const int t = threadIdx.x;
    const int base = blockIdx.x * 256;
    int v = (base + t < NT2) ? cnt[base + t] : 0;
    sm[t] = v;
    __syncthreads();
#pragma unroll
    for (int d = 1; d < 256; d <<= 1) {
        int add = (t >= d) ? sm[t - d] : 0;
        __syncthreads();
        sm[t] += add;
        __syncthreads();
    }
    if (base + t < NT2) offs[base + t] = sm[t] - v;  // local exclusive
    if (t == 255) bsum[blockIdx.x] = sm[255];
}

__global__ __launch_bounds__(512) void scan2_kernel(int* __restrict__ bsum,
                                                    int* __restrict__ total) {
    __shared__ int sm[512];
    const int t = threadIdx.x;
    int v = (t < NB2) ? bsum[t] : 0;
    sm[t] = v;
    __syncthreads();
#pragma unroll
    for (int d = 1; d < 512; d <<= 1) {
        int add = (t >= d) ? sm[t - d] : 0;
        __syncthreads();
        sm[t] += add;
        __syncthreads();
    }
    if (t < NB2) bsum[t] = sm[t] - v;
    if (t == 511) *total = sm[511];  // == 2*TOT_E
}

__global__ __launch_bounds__(256) void scan3_kernel(int* __restrict__ offs,
                                                    const int* __restrict__ bsum) {
    int i = blockIdx.x * blockDim.x + threadIdx.x;
    if (i < NT2) offs[i] += bsum[i >> 8];
}

__global__ __launch_bounds__(256) void scatter2_kernel(const int* __restrict__ ei_sp,
                                                       const int* __restrict__ ei_tp,
                                                       const int* __restrict__ offs,
                                                       const int* __restrict__ pos,
                                                       int* __restrict__ ssrc) {
    int i = blockIdx.x * blockDim.x + threadIdx.x;
    if (i >= 2 * TOT_E) return;
    int src, dstIdx;
    if (i < TOT_E) {
        src = (i < N_EDGES) ? ei_sp[i] : (i - N_EDGES);
        dstIdx = (i < N_EDGES) ? ei_sp[N_EDGES + i] : (i - N_EDGES);
    } else {
        int j = i - TOT_E;
        src = (j < N_EDGES) ? ei_tp[j] : (j - N_EDGES);
        dstIdx = N_NODES + ((j < N_EDGES) ? ei_tp[N_EDGES + j] : (j - N_EDGES));
    }
    ssrc[offs[dstIdx] + pos[i]] = src;  // atomic-free
}

// ---------------- pre-split passes (bf16 hi/lo) ----------------
__global__ __launch_bounds__(256) void split_x_kernel(const float* __restrict__ x,
                                                      ushort_t* __restrict__ Ah,
                                                      ushort_t* __restrict__ Al) {
    int i = blockIdx.x * 256 + threadIdx.x;  // over N*32 float4s (K=128)
    float4 v = ((const float4*)x)[i];
    float a[4] = {v.x, v.y, v.z, v.w};
    ushort_t h[4], lo[4];
#pragma unroll
    for (int q = 0; q < 4; ++q) {
        h[q] = bf16_rne(a[q]);
        float hf = __uint_as_float((unsigned int)h[q] << 16);
        lo[q] = bf16_rne(a[q] - hf);
    }
    *(uint2*)(Ah + (size_t)i * 4) = *(uint2*)h;
    *(uint2*)(Al + (size_t)i * 4) = *(uint2*)lo;
}

// BN(scale/shift from bnsum) + ReLU + split, for layer inputs 2..4
__global__ __launch_bounds__(256) void split_h_kernel(const float* __restrict__ y,
                                                      const double* __restrict__ sum,
                                                      const double* __restrict__ sqsum,
                                                      const float* __restrict__ g,
                                                      const float* __restrict__ be,
                                                      ushort_t* __restrict__ Ah,
                                                      ushort_t* __restrict__ Al) {
    __shared__ float scs[256], shs[256];
    const int t = threadIdx.x;
    {
        double mean = sum[t] / (double)N_NODES;
        double var = sqsum[t] / (double)N_NODES - mean * mean;
        float sc = g[t] * rsqrtf((float)var + 1e-5f);
        scs[t] = sc;
        shs[t] = be[t] - (float)mean * sc;
    }
    __syncthreads();
    int i = blockIdx.x * 256 + t;  // over N*64 float4s (exact)
    int c4 = (i & 63) << 2;
    float4 v = ((const float4*)y)[i];
    float a[4] = {fmaxf(0.f, fmaf(v.x, scs[c4 + 0], shs[c4 + 0])),
                  fmaxf(0.f, fmaf(v.y, scs[c4 + 1], shs[c4 + 1])),
                  fmaxf(0.f, fmaf(v.z, scs[c4 + 2], shs[c4 + 2])),
                  fmaxf(0.f, fmaf(v.w, scs[c4 + 3], shs[c4 + 3]))};
    ushort_t h[4], lo[4];
#pragma unroll
    for (int q = 0; q < 4; ++q) {
        h[q] = bf16_rne(a[q]);
        float hf = __uint_as_float((unsigned int)h[q] << 16);
        lo[q] = bf16_rne(a[q] - hf);
    }
    *(uint2*)(Ah + (size_t)i * 4) = *(uint2*)h;
    *(uint2*)(Al + (size_t)i * 4) = *(uint2*)lo;
}

// all 4 weight matrices -> col-major [256][K] bf16 hi/lo
__global__ __launch_bounds__(256) void split_ball_kernel(const float* __restrict__ W1,
                                                         const float* __restrict__ W2,
                                                         const float* __restrict__ W3,
                                                         const float* __restrict__ W4,
                                                         ushort_t* __restrict__ Bh,
                                                         ushort_t* __restrict__ Bl) {
    int i = blockIdx.x * 256 + threadIdx.x;  // over 229376 (exact: 896 blocks)
    int loc, kshift;
    const float* W;
    if (i < 32768) { W = W1; loc = i; kshift = 7; }
    else {
        int L = (i - 32768) >> 16;
        W = L == 0 ? W2 : L == 1 ? W3 : W4;
        loc = (i - 32768) & 65535;
        kshift = 8;
    }
    int c = loc >> kshift, kl = loc & ((1 << kshift) - 1);
    float v = W[(size_t)kl * 256 + c];
    ushort_t h = bf16_rne(v);
    float hf = __uint_as_float((unsigned int)h << 16);
    Bh[i] = h;
    Bl[i] = bf16_rne(v - hf);
}

// ---------------- MFMA GEMM (pre-split bf16, 3-product, reg-double-buffered) ----------------
__global__ __launch_bounds__(256) void gemm_kernel(const ushort_t* __restrict__ Ahg,
                                                   const ushort_t* __restrict__ Alg,
                                                   const ushort_t* __restrict__ Bhg,
                                                   const ushort_t* __restrict__ Blg,
                                                   __half* __restrict__ C,
                                                   const float* __restrict__ a_s,
                                                   const float* __restrict__ a_d,
                                                   float* __restrict__ als,
                                                   float* __restrict__ ald,
                                                   int M, int K) {
    __shared__ ushort_t Ah[128][40], Al[128][40];  // pad 40 (80B rows, 16B-aligned)
    __shared__ ushort_t Bh[128][40], Bl[128][40];
    const int t = threadIdx.x;
    const int l = t & 63;
    const int w = t >> 6;
    const int wr = w >> 1, wc = w & 1;
    const int fr = l & 15;
    const int kg = (l >> 4) << 3;
    const int bm = blockIdx.x * 128;
    const int bn = blockIdx.y * 128;
    const int sr = t >> 1;          // staging row (A) / col (B): 0..127
    const int sk = (t & 1) << 4;    // k-base 0 / 16
    const bool arow_ok = (bm + sr < M);

    f32x4 acc[4][4] = {};
    uint4 pa0, pa1, pl0, pl1, pb0, pb1, pc0, pc1;

#define LOADK(K0)                                                     \
    do {                                                              \
        const size_t abase = (size_t)(bm + sr) * K + (K0) + sk;       \
        if (arow_ok) {                                                \
            pa0 = *(const uint4*)(Ahg + abase);                       \
            pa1 = *(const uint4*)(Ahg + abase + 8);                   \
            pl0 = *(const uint4*)(Alg + abase);                       \
            pl1 = *(const uint4*)(Alg + abase + 8);                   \
        } else {                                                      \
            pa0 = pa1 = pl0 = pl1 = (uint4){0, 0, 0, 0};              \
        }                                                             \
        const size_t bbase = (size_t)(bn + sr) * K + (K0) + sk;       \
        pb0 = *(const uint4*)(Bhg + bbase);                           \
        pb1 = *(const uint4*)(Bhg + bbase + 8);                       \
        pc0 = *(const uint4*)(Blg + bbase);                           \
        pc1 = *(const uint4*)(Blg + bbase + 8);                       \
    } while (0)

    LOADK(0);
    for (int k0 = 0; k0 < K; k0 += 32) {
        *(uint4*)&Ah[sr][sk] = pa0; *(uint4*)&Ah[sr][sk + 8] = pa1;
        *(uint4*)&Al[sr][sk] = pl0; *(uint4*)&Al[sr][sk + 8] = pl1;
        *(uint4*)&Bh[sr][sk] = pb0; *(uint4*)&Bh[sr][sk + 8] = pb1;
        *(uint4*)&Bl[sr][sk] = pc0; *(uint4*)&Bl[sr][sk + 8] = pc1;
        __syncthreads();
        if (k0 + 32 < K) LOADK(k0 + 32);  // retire under the MFMA cluster

        short8 ahf[4], alf[4], bhf[4], blf[4];
#pragma unroll
        for (int m = 0; m < 4; ++m) {
            ahf[m] = *(const short8*)&Ah[wr * 64 + m * 16 + fr][kg];
            alf[m] = *(const short8*)&Al[wr * 64 + m * 16 + fr][kg];
        }
#pragma unroll
        for (int n = 0; n < 4; ++n) {
            bhf[n] = *(const short8*)&Bh[wc * 64 + n * 16 + fr][kg];
            blf[n] = *(const short8*)&Bl[wc * 64 + n * 16 + fr][kg];
        }
#pragma unroll
        for (int m = 0; m < 4; ++m)
#pragma unroll
            for (int n = 0; n < 4; ++n) {
                acc[m][n] = __builtin_amdgcn_mfma_f32_16x16x32_bf16(ahf[m], bhf[n], acc[m][n], 0, 0, 0);
                acc[m][n] = __builtin_amdgcn_mfma_f32_16x16x32_bf16(ahf[m], blf[n], acc[m][n], 0, 0, 0);
                acc[m][n] = __builtin_amdgcn_mfma_f32_16x16x32_bf16(alf[m], bhf[n], acc[m][n], 0, 0, 0);
            }
        __syncthreads();
    }
#undef LOADK

    // C write (fp16): col=lane&15, row=(lane>>4)*4+r  [m89-verified layout]
#pragma unroll
    for (int m = 0; m < 4; ++m) {
        const int row0 = bm + wr * 64 + m * 16 + ((l >> 4) << 2);
#pragma unroll
        for (int n = 0; n < 4; ++n) {
            const int col = bn + wc * 64 + n * 16 + fr;
#pragma unroll
            for (int r = 0; r < 4; ++r) {
                if (row0 + r < M)
                    C[(size_t)(row0 + r) * HC + col] = __float2half(acc[m][n][r]);
            }
        }
    }
    // fused als/ald epilogue: this wave's 64 cols == one head
    const int hw = (bn >> 6) + wc;
    float asv[4], adv[4];
#pragma unroll
    for (int n = 0; n < 4; ++n) {
        const int col = bn + wc * 64 + n * 16 + fr;
        asv[n] = a_s[col];
        adv[n] = a_d[col];
    }
#pragma unroll
    for (int m = 0; m < 4; ++m) {
        const int row0 = bm + wr * 64 + m * 16 + ((l >> 4) << 2);
#pragma unroll
        for (int r = 0; r < 4; ++r) {
            float ps = 0.f, pd = 0.f;
#pragma unroll
            for (int n = 0; n < 4; ++n) {
                ps = fmaf(acc[m][n][r], asv[n], ps);
                pd = fmaf(acc[m][n][r], adv[n], pd);
            }
#pragma unroll
            for (int d = 1; d < 16; d <<= 1) {
                ps += __shfl_xor(ps, d, 64);
                pd += __shfl_xor(pd, d, 64);
            }
            if (fr == 0 && row0 + r < M) {
                als[(row0 + r) * NH + hw] = ps;
                ald[(row0 + r) * NH + hw] = pd;
            }
        }
    }
}

// ---------------- GAT aggregation: one wave per dst ----------------
__global__ __launch_bounds__(256) void gat_edge_kernel(const __half* __restrict__ h,
                                                       const int* __restrict__ offs,
                                                       const int* __restrict__ ssrc,
                                                       const float* __restrict__ als,
                                                       const float* __restrict__ ald,
                                                       const float* __restrict__ bias,
                                                       float* __restrict__ out) {
    __shared__ float ex_sm[4][64][NH];
    __shared__ int   src_sm[4][64];
    const int lane = threadIdx.x & 63;
    const int w = threadIdx.x >> 6;
    const int v = (blockIdx.x << 2) + w;
    const int ehalf = lane >> 5;      // 0: even edges, 1: odd edges
    const int cl = lane & 31;         // channels 8*cl .. 8*cl+7
    const int hh2 = cl >> 3;          // accumulation head
    const float4 aldv4 = *(const float4*)(ald + v * NH);
    const int beg = offs[v], end = offs[v + 1];  // degree >= 1 (self-loop)

    float4 m4 = make_float4(-INFINITY, -INFINITY, -INFINITY, -INFINITY);
    float4 s4 = make_float4(0.f, 0.f, 0.f, 0.f);
    float acc8[8] = {0.f};

    for (int c0 = beg; c0 < end; c0 += 64) {
        const int n = min(64, end - c0);
        // ---- phase 1: lane-per-edge ----
        int srcl = ssrc[c0];
        float4 e4 = make_float4(-INFINITY, -INFINITY, -INFINITY, -INFINITY);
        if (lane < n) {
            srcl = ssrc[c0 + lane];
            float4 a4 = *(const float4*)(als + srcl * NH);
            e4.x = lrelu(a4.x + aldv4.x);
            e4.y = lrelu(a4.y + aldv4.y);
            e4.z = lrelu(a4.z + aldv4.z);
            e4.w = lrelu(a4.w + aldv4.w);
        }
        float4 cm = e4;
#pragma unroll
        for (int d = 1; d < 64; d <<= 1) {
            cm.x = fmaxf(cm.x, __shfl_xor(cm.x, d, 64));
            cm.y = fmaxf(cm.y, __shfl_xor(cm.y, d, 64));
            cm.z = fmaxf(cm.z, __shfl_xor(cm.z, d, 64));
            cm.w = fmaxf(cm.w, __shfl_xor(cm.w, d, 64));
        }
        const float4 mn = make_float4(fmaxf(m4.x, cm.x), fmaxf(m4.y, cm.y),
                                      fmaxf(m4.z, cm.z), fmaxf(m4.w, cm.w));
        const float4 r4 = make_float4(__expf(m4.x - mn.x), __expf(m4.y - mn.y),
                                      __expf(m4.z - mn.z), __expf(m4.w - mn.w));
        float4 ex4;  // 0 for inactive lanes
        ex4.x = __expf(e4.x - mn.x);
        ex4.y = __expf(e4.y - mn.y);
        ex4.z = __expf(e4.z - mn.z);
        ex4.w = __expf(e4.w - mn.w);
        src_sm[w][lane] = srcl;
        *(float4*)&ex_sm[w][lane][0] = ex4;
        s4 = make_float4(fmaf(s4.x, r4.x, ex4.x), fmaf(s4.y, r4.y, ex4.y),
                         fmaf(s4.z, r4.z, ex4.z), fmaf(s4.w, r4.w, ex4.w));
        const float rh2 = hh2 == 0 ? r4.x : hh2 == 1 ? r4.y : hh2 == 2 ? r4.z : r4.w;
#pragma unroll
        for (int i = 0; i < 8; ++i) acc8[i] *= rh2;
        m4 = mn;

        // ---- phase 2: 16B/lane gather (2 edges per load instruction) ----
        const int trip = (n + 7) & ~7;  // padded entries have weight 0
        const int co2 = cl << 3;        // fp16 channel offset
        for (int j = 0; j < trip; j += 8) {
            uint4 raw[4];
            float u[4];
#pragma unroll
            for (int q = 0; q < 4; ++q) {
                const int e = j + 2 * q + ehalf;
                const int s = src_sm[w][e];
                raw[q] = *(const uint4*)(h + (size_t)s * HC + co2);
                u[q] = ex_sm[w][e][hh2];
            }
#pragma unroll
            for (int q = 0; q < 4; ++q) {
                const __half2* p = reinterpret_cast<const __half2*>(&raw[q]);
#pragma unroll
                for (int z = 0; z < 4; ++z) {
                    const float2 f = __half22float2(p[z]);
                    acc8[2 * z]     = fmaf(u[q], f.x, acc8[2 * z]);
                    acc8[2 * z + 1] = fmaf(u[q], f.y, acc8[2 * z + 1]);
                }
            }
        }
    }

    // combine the two half-waves (lane l and l^32 hold the same channels)
#pragma unroll
    for (int i = 0; i < 8; ++i) acc8[i] += __shfl_xor(acc8[i], 32, 64);
    // reduce the per-lane softmax denominators
#pragma unroll
    for (int d = 1; d < 64; d <<= 1) {
        s4.x += __shfl_xor(s4.x, d, 64);
        s4.y += __shfl_xor(s4.y, d, 64);
        s4.z += __shfl_xor(s4.z, d, 64);
        s4.w += __shfl_xor(s4.w, d, 64);
    }
    const float sh = hh2 == 0 ? s4.x : hh2 == 1 ? s4.y : hh2 == 2 ? s4.z : s4.w;
    const float inv = 1.f / (sh + 1e-16f);
    if (ehalf == 0) {
        const int cb = cl << 3;
        const float4 b0 = *(const float4*)(bias + cb);
        const float4 b1 = *(const float4*)(bias + cb + 4);
        *(float4*)(out + (size_t)v * HC + cb) =
            make_float4(fmaf(acc8[0], inv, b0.x), fmaf(acc8[1], inv, b0.y),
                        fmaf(acc8[2], inv, b0.z), fmaf(acc8[3], inv, b0.w));
        *(float4*)(out + (size_t)v * HC + cb + 4) =
            make_float4(fmaf(acc8[4], inv, b1.x), fmaf(acc8[5], inv, b1.y),
                        fmaf(acc8[6], inv, b1.z), fmaf(acc8[7], inv, b1.w));
    }
}

// ---------------- BatchNorm stats ----------------
__global__ __launch_bounds__(256) void bn_stats_kernel(const float* __restrict__ y,
                                                       double* __restrict__ sum,
                                                       double* __restrict__ sqsum) {
    const int t = threadIdx.x;
    const int r0 = blockIdx.x * 128;
    const int r1 = min(r0 + 128, N_NODES);
    float s = 0.f, q = 0.f;
    for (int r = r0; r < r1; ++r) {
        float v = y[(size_t)r * HC + t];
        s += v;
        q = fmaf(v, v, q);
    }
    atomicAdd(&sum[t], (double)s);
    atomicAdd(&sqsum[t], (double)q);
}

// ---------------- final linear (BN from bnsum computed in-block) ----------------
__global__ __launch_bounds__(256) void linear_kernel(const float* __restrict__ y,
                                                     const float* __restrict__ Wl,
                                                     const float* __restrict__ bl,
                                                     const double* __restrict__ sum,
                                                     const double* __restrict__ sqsum,
                                                     const float* __restrict__ g,
                                                     const float* __restrict__ be,
                                                     float* __restrict__ out) {
    __shared__ float Wls[256 * 32];
    __shared__ float scs[256], shs[256];
    const int t = threadIdx.x;
    {
        double mean = sum[t] / (double)N_NODES;
        double var = sqsum[t] / (double)N_NODES - mean * mean;
        float sc = g[t] * rsqrtf((float)var + 1e-5f);
        scs[t] = sc;
        shs[t] = be[t] - (float)mean * sc;
    }
    for (int i = t; i < 256 * 32; i += 256) Wls[i] = Wl[i];
    __syncthreads();
    int gid = blockIdx.x * 256 + t;
    int n = gid >> 5, j = gid & 31;
    float acc = bl[j];
    const float4* yrow = (const float4*)(y + (size_t)n * HC);
#pragma unroll
    for (int k4 = 0; k4 < 64; ++k4) {
        float4 y4 = yrow[k4];
        int k = k4 << 2;
        y4.x = fmaxf(0.f, fmaf(y4.x, scs[k + 0], shs[k + 0]));
        y4.y = fmaxf(0.f, fmaf(y4.y, scs[k + 1], shs[k + 1]));
        y4.z = fmaxf(0.f, fmaf(y4.z, scs[k + 2], shs[k + 2]));
        y4.w = fmaxf(0.f, fmaf(y4.w, scs[k + 3], shs[k + 3]));
        acc = fmaf(y4.x, Wls[(k + 0) * 32 + j], acc);
        acc = fmaf(y4.y, Wls[(k + 1) * 32 + j], acc);
        acc = fmaf(y4.z, Wls[(k + 2) * 32 + j], acc);
        acc = fmaf(y4.w, Wls[(k + 3) * 32 + j], acc);
    }
    out[gid] = acc;
}

extern "C" void kernel_launch(void* const* d_in, const int* in_sizes, int n_in,
                              void* d_out, int out_size, void* d_ws, size_t ws_size,
                              hipStream_t stream) {
    const float* x   = (const float*)d_in[0];
    const int* ei_sp = (const int*)d_in[1];
    const int* ei_tp = (const int*)d_in[2];
    const float* Wl  = (const float*)d_in[27];
    const float* bl  = (const float*)d_in[28];

    char* ws = (char*)d_ws;
    size_t off = 0;
    auto alloc = [&](size_t bytes) -> char* {
        char* p = ws + off;
        off = (off + bytes + 255) & ~(size_t)255;
        return p;
    };
    ushort_t* AhA  = (ushort_t*)alloc((size_t)N_NODES * HC * 2);   // 25.6 MB
    ushort_t* AlA  = (ushort_t*)alloc((size_t)N_NODES * HC * 2);   // 25.6 MB
    __half* buf0   = (__half*)alloc((size_t)N_NODES * HC * 2);     // gemm out h (fp16)
    float* buf1    = (float*)alloc((size_t)N_NODES * HC * 4);      // gat out (fp32)
    float* als     = (float*)alloc((size_t)N_NODES * NH * 4);
    float* ald     = (float*)alloc((size_t)N_NODES * NH * 4);
    int*  offs_all = (int*)alloc((size_t)(NT2 + 1) * 4);
    int*  ssrc_all = (int*)alloc((size_t)2 * TOT_E * 4);
    int*  posbuf   = (int*)alloc((size_t)2 * TOT_E * 4);
    int*  cnt_all  = (int*)alloc((size_t)NT2 * 4);
    int*  bsum     = (int*)alloc((size_t)NB2 * 4);
    ushort_t* BhA  = (ushort_t*)alloc((size_t)229376 * 2);
    ushort_t* BlA  = (ushort_t*)alloc((size_t)229376 * 2);
    double* bnsum  = (double*)alloc(256 * 8 * 2);
    double* bnsq   = bnsum + 256;
    (void)ws_size; (void)in_sizes; (void)n_in; (void)out_size;

    const int EB2 = (2 * TOT_E + 255) / 256;
    const int offB[4] = {0, 32768, 98304, 163840};

    // ---- CSR for both edge types, one pipeline, single atomic pass ----
    hipMemsetAsync(cnt_all, 0, (size_t)NT2 * 4, stream);
    count2_kernel<<<EB2, 256, 0, stream>>>(ei_sp, ei_tp, cnt_all, posbuf);
    scan1_kernel<<<NB2, 256, 0, stream>>>(cnt_all, offs_all, bsum);
    scan2_kernel<<<1, 512, 0, stream>>>(bsum, offs_all + NT2);
    scan3_kernel<<<NB2, 256, 0, stream>>>(offs_all, bsum);
    scatter2_kernel<<<EB2, 256, 0, stream>>>(ei_sp, ei_tp, offs_all, posbuf, ssrc_all);

    // ---- one-time splits ----
    split_x_kernel<<<N_NODES * 32 / 256, 256, 0, stream>>>(x, AhA, AlA);
    split_ball_kernel<<<896, 256, 0, stream>>>((const float*)d_in[3], (const float*)d_in[9],
                                               (const float*)d_in[15], (const float*)d_in[21],
                                               BhA, BlA);

    // ---- 4 GAT layers ----
    const int NB4 = N_NODES / 4;                 // 12500
    const dim3 ggrid((N_NODES + 127) / 128, 2);  // 391 x 2
    for (int L = 0; L < 4; ++L) {
        const int K = (L == 0) ? 128 : 256;
        const int* offs = (L < 2) ? offs_all : (offs_all + N_NODES);
        const int base = 3 + L * 6;
        const float* as_ = (const float*)d_in[base + 1];
        const float* ad_ = (const float*)d_in[base + 2];
        const float* b_  = (const float*)d_in[base + 3];

        if (L > 0) {
            const int pbase = 3 + (L - 1) * 6;
            split_h_kernel<<<N_NODES * 64 / 256, 256, 0, stream>>>(
                buf1, bnsum, bnsq, (const float*)d_in[pbase + 4],
                (const float*)d_in[pbase + 5], AhA, AlA);
        }
        gemm_kernel<<<ggrid, 256, 0, stream>>>(AhA, AlA, BhA + offB[L], BlA + offB[L],
                                               buf0, as_, ad_, als, ald, N_NODES, K);
        gat_edge_kernel<<<NB4, 256, 0, stream>>>(buf0, offs, ssrc_all, als, ald, b_, buf1);

        hipMemsetAsync(bnsum, 0, 256 * 8 * 2, stream);
        bn_stats_kernel<<<(N_NODES + 127) / 128, 256, 0, stream>>>(buf1, bnsum, bnsq);
    }

    // ---- final linear (fused relu(bn(.)) of layer 4) ----
    linear_kernel<<<N_NODES * 32 / 256, 256, 0, stream>>>(
        buf1, Wl, bl, bnsum, bnsq, (const float*)d_in[25], (const float*)d_in[26],
        (float*)d_out);
}